// Round 3
// baseline (254.958 us; speedup 1.0000x reference)
//
#include <hip/hip_runtime.h>
#include <hip/hip_bf16.h>
#include <stdint.h>

// CostVolumeAttention2: B=2, N=8192, C=512, heads=8, hd=64, T=8, H=W=32, U=49.
// Linearized softmax: |M|<=49/64^2=0.012 -> exp(M)=1+M to 7e-5 rel accuracy.
// attn @ v collapses to rank-50:  num = A'^T (A' v),  den = A'^T (A' 1),
// where A' = corr with an appended ones-row (u=49), zero pad to 64 rows.

#define DEVFN __device__ __forceinline__

typedef __attribute__((ext_vector_type(8))) short bf16x8;
typedef __attribute__((ext_vector_type(4))) float f32x4;

DEVFN float bf2f(short s) {
  union { unsigned int u; float f; } v;
  v.u = ((unsigned int)(unsigned short)s) << 16;
  return v.f;
}
DEVFN short f2bf(float f) {
  __hip_bfloat16 h = __float2bfloat16(f);
  return *reinterpret_cast<short*>(&h);
}

DEVFN void gl_lds16(const void* g, void* l) {
  __builtin_amdgcn_global_load_lds((const __attribute__((address_space(1))) void*)g,
                                   (__attribute__((address_space(3))) void*)l, 16, 0, 0);
}

#define MFMA(a, b, c) __builtin_amdgcn_mfma_f32_16x16x32_bf16((a), (b), (c), 0, 0, 0)

#define NTOK 8192
#define HW   1024

// ---------------------------------------------------------------- fp32->bf16
__global__ void k_cvt(const float* __restrict__ in, short* __restrict__ out, int n8) {
  int i = blockIdx.x * blockDim.x + threadIdx.x;
  if (i >= n8) return;
  const float4* p = (const float4*)in + (size_t)i * 2;
  float4 a = p[0], b = p[1];
  bf16x8 r;
  r[0]=f2bf(a.x); r[1]=f2bf(a.y); r[2]=f2bf(a.z); r[3]=f2bf(a.w);
  r[4]=f2bf(b.x); r[5]=f2bf(b.y); r[6]=f2bf(b.z); r[7]=f2bf(b.w);
  *(bf16x8*)(out + (size_t)i * 8) = r;
}

// ------------------------------------------------- GEMM: C[M][N] = A * B^T
template<int F32OUT>
__global__ __launch_bounds__(256, 2) void k_gemm_bt(
    const short* __restrict__ A, const short* __restrict__ Bm,
    void* __restrict__ Cp, const float* __restrict__ bias, int M, int N, int K)
{
  __shared__ short lA[128 * 64];
  __shared__ short lB[128 * 64];
  const int tid = threadIdx.x;
  const int lane = tid & 63, w = tid >> 6;
  const int wm = w >> 1, wn = w & 1;
  const int r15 = lane & 15, hi = (lane >> 4) * 16, g4 = (lane >> 4) * 4;
  const int m0 = blockIdx.y * 128, n0 = blockIdx.x * 128;

  f32x4 acc[4][4];
#pragma unroll
  for (int i = 0; i < 4; i++)
#pragma unroll
    for (int j = 0; j < 4; j++) acc[i][j] = (f32x4)0.f;

  for (int k0 = 0; k0 < K; k0 += 64) {
#pragma unroll
    for (int it = 0; it < 4; it++) {
      int chunk = it * 256 + tid;
      int row = chunk >> 3;
      int sb = ((chunk & 7) * 16) ^ ((row & 7) << 4);
      const char* srcA = (const char*)(A + (size_t)(m0 + row) * K + k0) + sb;
      const char* srcB = (const char*)(Bm + (size_t)(n0 + row) * K + k0) + sb;
      short* dA = lA + (it * 256 + w * 64) * 8;
      short* dB = lB + (it * 256 + w * 64) * 8;
      gl_lds16(srcA, dA);
      gl_lds16(srcB, dB);
    }
    asm volatile("s_waitcnt vmcnt(0)" ::: "memory");
    __syncthreads();

    bf16x8 af[4][2], bfr[4][2];
#pragma unroll
    for (int mt = 0; mt < 4; mt++) {
      int row = wm * 64 + mt * 16 + r15;
#pragma unroll
      for (int kh = 0; kh < 2; kh++) {
        int off = row * 128 + ((kh * 64 + hi) ^ ((row & 7) << 4));
        af[mt][kh] = *(const bf16x8*)((const char*)lA + off);
      }
    }
#pragma unroll
    for (int nt = 0; nt < 4; nt++) {
      int row = wn * 64 + nt * 16 + r15;
#pragma unroll
      for (int kh = 0; kh < 2; kh++) {
        int off = row * 128 + ((kh * 64 + hi) ^ ((row & 7) << 4));
        bfr[nt][kh] = *(const bf16x8*)((const char*)lB + off);
      }
    }
#pragma unroll
    for (int mt = 0; mt < 4; mt++)
#pragma unroll
      for (int nt = 0; nt < 4; nt++) {
        acc[mt][nt] = MFMA(af[mt][0], bfr[nt][0], acc[mt][nt]);
        acc[mt][nt] = MFMA(af[mt][1], bfr[nt][1], acc[mt][nt]);
      }
    __syncthreads();
  }

#pragma unroll
  for (int mt = 0; mt < 4; mt++)
#pragma unroll
    for (int j = 0; j < 4; j++) {
      int row = m0 + wm * 64 + mt * 16 + g4 + j;
#pragma unroll
      for (int nt = 0; nt < 4; nt++) {
        int col = n0 + wn * 64 + nt * 16 + r15;
        float v = acc[mt][nt][j];
        if (F32OUT) ((float*)Cp)[(size_t)row * N + col] = v + bias[col];
        else        ((short*)Cp)[(size_t)row * N + col] = f2bf(v);
      }
    }
}

// ---------------------------------------------------------------- cost volume
// 512 blocks: one per (bht, y-octet). Rolling 8-slot k-row window in LDS
// (slot = krow & 7); per y-iteration prefetch exactly one new k row while
// computing the current y via MFMA. Amortizes the per-block staging/drain
// latency that dominated the 4096-block version.
__global__ __launch_bounds__(256, 2) void k_corr(
    const short* __restrict__ qkvb, short* __restrict__ corrI, short* __restrict__ corrU)
{
  __shared__ short lq[256 * 64];   // 8 y-rows x 32 px x 128B = 32KB
  __shared__ short lk[256 * 64];   // 8 slots x 32 px x 128B = 32KB
  __shared__ short tI[32 * 64];    // out tile [x][u] for current y
  __shared__ short tU[64 * 32];    // out tile [u][x]
  __shared__ float sq[256];        // q px scales
  __shared__ float skb[8][32];     // k px scales per slot

  const int tid = threadIdx.x;
  const int lane = tid & 63, w = tid >> 6;
  const int r15 = lane & 15, hi = (lane >> 4) * 16, g4 = (lane >> 4) * 4;
  const int px = tid >> 3, part = tid & 7;
  const int sb = (part * 16) ^ ((px & 7) << 4);
  const int bht = blockIdx.x >> 2, y0 = (blockIdx.x & 3) * 8;
  const int b = bht >> 6, head = (bht >> 3) & 7, tf = bht & 7;
  const int tk = (tf < 7) ? tf + 1 : 7;
  const size_t qbase = ((size_t)b * NTOK + tf * HW) * 1536 + head * 64;
  const size_t kbase = ((size_t)b * NTOK + tk * HW) * 1536 + 512 + head * 64;

  // zeroing vectors with the u=49 "ones" fused in (avoids a zero-then-ones race)
  const short ONE = f2bf(1.f);
  bf16x8 zI = (bf16x8)(short)0;
  if ((tid & 7) == 6) zI[1] = ONE;          // tI[x][48..55] chunk, elem 1 -> u=49
  bf16x8 zU = (bf16x8)(short)0;
  if ((tid >> 2) == 49) {                    // tU row u=49 chunks
#pragma unroll
    for (int e = 0; e < 8; e++) zU[e] = ONE;
  }

  *(bf16x8*)(tI + tid * 8) = zI;
  *(bf16x8*)(tU + tid * 8) = zU;

  // prologue stage: 8 q rows, k rows y0-3..y0+3
#pragma unroll
  for (int jj = 0; jj < 8; jj++)
    gl_lds16((const char*)(qkvb + qbase + (size_t)((y0 + jj) * 32 + px) * 1536) + sb,
             lq + jj * 2048 + w * 512);
#pragma unroll
  for (int dy = 0; dy < 7; dy++) {
    int r = y0 + dy - 3, slot = r & 7;
    if (r >= 0 && r < 32)
      gl_lds16((const char*)(qkvb + kbase + (size_t)(r * 32 + px) * 1536) + sb,
               lk + slot * 2048 + w * 512);
    else
      *(bf16x8*)(lk + slot * 2048 + tid * 8) = (bf16x8)(short)0;
  }
  asm volatile("s_waitcnt vmcnt(0)" ::: "memory");
  __syncthreads();

  { // q norms: thread t -> physical q row t
    float ss = 0.f;
#pragma unroll
    for (int jj = 0; jj < 8; jj++) {
      int off = tid * 128 + ((jj * 16) ^ ((tid & 7) << 4));
      bf16x8 vv = *(const bf16x8*)((const char*)lq + off);
#pragma unroll
      for (int e = 0; e < 8; e++) { float f = bf2f(vv[e]); ss += f * f; }
    }
    sq[tid] = 1.f / (8.f * fmaxf(sqrtf(ss), 1e-12f));
  }
  if (tid < 224) { // k norms for the 7 prologue rows
    int dy = tid >> 5, xx = tid & 31;
    int r = y0 + dy - 3, slot = r & 7;
    float sc = 0.f;
    if (r >= 0 && r < 32) {
      float ss = 0.f;
#pragma unroll
      for (int jj = 0; jj < 8; jj++) {
        int off = slot * 4096 + xx * 128 + ((jj * 16) ^ ((xx & 7) << 4));
        bf16x8 vv = *(const bf16x8*)((const char*)lk + off);
#pragma unroll
        for (int e = 0; e < 8; e++) { float f = bf2f(vv[e]); ss += f * f; }
      }
      sc = 1.f / (8.f * fmaxf(sqrtf(ss), 1e-12f));
    }
    skb[slot][xx] = sc;
  }
  __syncthreads();

#pragma unroll 1
  for (int j = 0; j < 8; j++) {
    const int y = y0 + j;
    const int rn = y + 4, slotn = rn & 7;

    // 1. prefetch next k row (overlaps with compute below)
    if (j < 7) {
      if (rn < 32)
        gl_lds16((const char*)(qkvb + kbase + (size_t)(rn * 32 + px) * 1536) + sb,
                 lk + slotn * 2048 + w * 512);
      else
        *(bf16x8*)(lk + slotn * 2048 + tid * 8) = (bf16x8)(short)0;
    }

    // 2. MFMA: q rows (this y) x 224-px k window
    bf16x8 aq[2][2];
#pragma unroll
    for (int mt = 0; mt < 2; mt++) {
      int row = mt * 16 + r15;
#pragma unroll
      for (int kh = 0; kh < 2; kh++) {
        int off = (j * 32 + row) * 128 + ((kh * 64 + hi) ^ ((row & 7) << 4));
        aq[mt][kh] = *(const bf16x8*)((const char*)lq + off);
      }
    }
    f32x4 accc[7];
#pragma unroll
    for (int c = 0; c < 7; c++) {
      int t = w * 7 + c, mt = t & 1, nt = t >> 1;
      int dy = nt >> 1, xx = (nt & 1) * 16 + r15;
      int slot = (y + dy - 3) & 7;
      f32x4 a = (f32x4)0.f;
#pragma unroll
      for (int kh = 0; kh < 2; kh++) {
        int off = slot * 4096 + xx * 128 + ((kh * 64 + hi) ^ ((xx & 7) << 4));
        bf16x8 bb = *(const bf16x8*)((const char*)lk + off);
        a = MFMA(aq[mt][kh], bb, a);
      }
      accc[c] = a;
    }

    // extract banded diagonals into LDS tiles
#pragma unroll
    for (int c = 0; c < 7; c++) {
      int t = w * 7 + c, mt = t & 1, nt = t >> 1;
      int dy = nt >> 1, xx = (nt & 1) * 16 + r15;
      int slot = (y + dy - 3) & 7;
      float skv = skb[slot][xx];
#pragma unroll
      for (int jj = 0; jj < 4; jj++) {
        int xr = mt * 16 + g4 + jj;
        int dx = xx - xr + 3;
        if (dx >= 0 && dx < 7) {
          int u = dy * 7 + dx;
          short bv = f2bf(accc[c][jj] * sq[j * 32 + xr] * skv);
          tI[xr * 64 + u] = bv;
          tU[u * 32 + xr] = bv;
        }
      }
    }
    __syncthreads();  // 3. tiles complete

    // 4. coalesced writeback
    *(bf16x8*)(corrI + ((size_t)bht * HW + y * 32) * 64 + tid * 8) = *(const bf16x8*)(tI + tid * 8);
    {
      int u = tid >> 2, qq = tid & 3;
      *(bf16x8*)(corrU + (size_t)bht * 65536 + u * HW + y * 32 + qq * 8) = *(const bf16x8*)(tU + u * 32 + qq * 8);
    }

    if (j < 7) {
      // 5. drain prefetch + ensure writeback LDS reads done
      asm volatile("s_waitcnt vmcnt(0)" ::: "memory");
      __syncthreads();
      // 6. re-zero tiles (+ones) and compute norms for the new row
      *(bf16x8*)(tI + tid * 8) = zI;
      *(bf16x8*)(tU + tid * 8) = zU;
      if (tid < 32) {
        float sc = 0.f;
        if (rn < 32) {
          float ss = 0.f;
#pragma unroll
          for (int jj = 0; jj < 8; jj++) {
            int off = slotn * 4096 + tid * 128 + ((jj * 16) ^ ((tid & 7) << 4));
            bf16x8 vv = *(const bf16x8*)((const char*)lk + off);
#pragma unroll
            for (int e = 0; e < 8; e++) { float f = bf2f(vv[e]); ss += f * f; }
          }
          sc = 1.f / (8.f * fmaxf(sqrtf(ss), 1e-12f));
        }
        skb[slotn][tid] = sc;
      }
      __syncthreads();  // 7. norms + re-zero visible
    }
  }
}

// ----------------------------------------------- v transpose: vT[bht][d][i]
__global__ __launch_bounds__(256, 2) void k_vT(const short* __restrict__ qkvb, short* __restrict__ vT)
{
  __shared__ short lt[128 * 72];  // [i][d] pad 72
  const int tid = threadIdx.x;
  const int bht = blockIdx.x >> 2;
  const int cbase = (blockIdx.x & 3) * 256;
  const int b = bht >> 6, head = (bht >> 3) & 7, tf = bht & 7;
  const size_t rowbase = ((size_t)b * NTOK + tf * HW) * 1536 + 1024 + head * 64;
  for (int c0 = cbase; c0 < cbase + 256; c0 += 128) {
    __syncthreads();
#pragma unroll
    for (int it = 0; it < 4; it++) {
      int idx = it * 256 + tid;
      int row = idx >> 3, part = idx & 7;
      bf16x8 v = *(const bf16x8*)(qkvb + rowbase + (size_t)(c0 + row) * 1536 + part * 8);
      *(bf16x8*)(lt + row * 72 + part * 8) = v;
    }
    __syncthreads();
    int d = tid & 63, blk = tid >> 6;
#pragma unroll
    for (int qq = 0; qq < 4; qq++) {
      bf16x8 o;
#pragma unroll
      for (int e = 0; e < 8; e++) o[e] = lt[(blk * 32 + qq * 8 + e) * 72 + d];
      *(bf16x8*)(vT + ((size_t)bht * 64 + d) * HW + c0 + blk * 32 + qq * 8) = o;
    }
  }
}

// --------------------------------- fused rank-50 attention, one WG per bht
__global__ __launch_bounds__(256, 2) void k_attn(
    const short* __restrict__ corrU, const short* __restrict__ corrI,
    const short* __restrict__ vT, short* __restrict__ out_attn)
{
  __shared__ short lV[64 * 64];
  __shared__ short lU[64 * 64];
  __shared__ short GTl[64 * 72];
  __shared__ float cl[64];
  __shared__ float cpart[256];
  const int tid = threadIdx.x, lane = tid & 63, w = tid >> 6;
  const int r15 = lane & 15, hi = (lane >> 4) * 16, g4 = (lane >> 4) * 4, g8 = (lane >> 4) * 8;
  const int bht = blockIdx.x;
  const int b = bht >> 6, head = (bht >> 3) & 7, tf = bht & 7;

  f32x4 accP[4];
#pragma unroll
  for (int nt = 0; nt < 4; nt++) accP[nt] = (f32x4)0.f;
  float c1p = 0.f;
  const short* vbase = vT + (size_t)bht * 64 * HW;
  const short* ubase = corrU + (size_t)bht * 65536;

  for (int i0 = 0; i0 < 1024; i0 += 64) {
#pragma unroll
    for (int it = 0; it < 2; it++) {
      int chunk = it * 256 + tid;
      int row = chunk >> 3;
      int sb = ((chunk & 7) * 16) ^ ((row & 7) << 4);
      gl_lds16((const char*)(vbase + (size_t)row * HW + i0) + sb, lV + (it * 256 + w * 64) * 8);
      gl_lds16((const char*)(ubase + (size_t)row * HW + i0) + sb, lU + (it * 256 + w * 64) * 8);
    }
    asm volatile("s_waitcnt vmcnt(0)" ::: "memory");
    __syncthreads();
    bf16x8 av[2];
    int rowA = w * 16 + r15;
#pragma unroll
    for (int kh = 0; kh < 2; kh++) {
      int off = rowA * 128 + ((kh * 64 + hi) ^ ((rowA & 7) << 4));
      av[kh] = *(const bf16x8*)((const char*)lV + off);
    }
#pragma unroll
    for (int nt = 0; nt < 4; nt++) {
      int rowB = nt * 16 + r15;
#pragma unroll
      for (int kh = 0; kh < 2; kh++) {
        int off = rowB * 128 + ((kh * 64 + hi) ^ ((rowB & 7) << 4));
        bf16x8 bu = *(const bf16x8*)((const char*)lU + off);
        accP[nt] = MFMA(av[kh], bu, accP[nt]);
      }
    }
    { // c1 partials
      int u = tid >> 2, partc = tid & 3;
#pragma unroll
      for (int h = 0; h < 2; h++) {
        int off = u * 128 + ((partc * 32 + h * 16) ^ ((u & 7) << 4));
        bf16x8 vv = *(const bf16x8*)((const char*)lU + off);
#pragma unroll
        for (int e = 0; e < 8; e++) c1p += bf2f(vv[e]);
      }
    }
    __syncthreads();
  }
  cpart[tid] = c1p;
#pragma unroll
  for (int nt = 0; nt < 4; nt++)
#pragma unroll
    for (int j = 0; j < 4; j++) {
      int d = w * 16 + g4 + j, u = nt * 16 + r15;
      GTl[d * 72 + u] = f2bf(accP[nt][j]);
    }
  __syncthreads();
  if (tid < 64) cl[tid] = cpart[4 * tid] + cpart[4 * tid + 1] + cpart[4 * tid + 2] + cpart[4 * tid + 3];
  __syncthreads();

  bf16x8 gtb[4][2];
#pragma unroll
  for (int nt = 0; nt < 4; nt++)
#pragma unroll
    for (int kh = 0; kh < 2; kh++)
      gtb[nt][kh] = *(const bf16x8*)((const char*)GTl + (nt * 16 + r15) * 144 + kh * 64 + hi);

  float c1r[2][8];
#pragma unroll
  for (int kh = 0; kh < 2; kh++)
#pragma unroll
    for (int e = 0; e < 8; e++) c1r[kh][e] = cl[kh * 32 + g8 + e];

  const short* ibase = corrI + (size_t)bht * HW * 64;
  for (int s = 0; s < 16; s++) {
    int i0 = w * 256 + s * 16;
    bf16x8 af[2];
#pragma unroll
    for (int kh = 0; kh < 2; kh++)
      af[kh] = *(const bf16x8*)(ibase + (size_t)(i0 + r15) * 64 + kh * 32 + g8);
    f32x4 a2[4];
#pragma unroll
    for (int nt = 0; nt < 4; nt++) a2[nt] = (f32x4)0.f;
#pragma unroll
    for (int nt = 0; nt < 4; nt++)
#pragma unroll
      for (int kh = 0; kh < 2; kh++) a2[nt] = MFMA(af[kh], gtb[nt][kh], a2[nt]);

    float dp = 0.f;
#pragma unroll
    for (int kh = 0; kh < 2; kh++)
#pragma unroll
      for (int e = 0; e < 8; e++) dp += bf2f(af[kh][e]) * c1r[kh][e];
    dp += __shfl_xor(dp, 16);
    dp += __shfl_xor(dp, 32);

#pragma unroll
    for (int j = 0; j < 4; j++) {
      float dj = __shfl(dp, g4 + j);
      float inv = 1.f / dj;
      int i = i0 + g4 + j;
      size_t outrow = ((size_t)b * NTOK + tf * HW + i) * 512 + head * 64;
#pragma unroll
      for (int nt = 0; nt < 4; nt++)
        out_attn[outrow + nt * 16 + r15] = f2bf(a2[nt][j] * inv);
    }
  }
}

extern "C" void kernel_launch(void* const* d_in, const int* in_sizes, int n_in,
                              void* d_out, int out_size, void* d_ws, size_t ws_size,
                              hipStream_t stream) {
  (void)in_sizes; (void)n_in; (void)out_size; (void)ws_size;
  const float* x      = (const float*)d_in[0];
  const float* w_qkv  = (const float*)d_in[1];
  const float* w_proj = (const float*)d_in[2];
  const float* b_proj = (const float*)d_in[3];

  char* ws = (char*)d_ws;
  short* qkvb   = (short*)(ws);                 // 50,331,648 B [16384][1536]
  short* xb     = (short*)(ws + 50331648);      // 16,777,216 B
  short* corrU  = (short*)(ws + 67108864);      // 16,777,216 B [128][64][1024]
  short* vT     = (short*)(ws + 83886080);      // 16,777,216 B [128][64][1024]
  short* wqkvb  = (short*)(ws + 100663296);     //  1,572,864 B
  short* wprojb = (short*)(ws + 102236160);     //    524,288 B
  short* corrI    = xb;    // alias: xb dead after qkv GEMM
  short* out_attn = qkvb;  // alias: qkvb dead after corr + vT

  k_cvt<<<dim3(4096), 256, 0, stream>>>(x, xb, 1048576);
  k_cvt<<<dim3(384),  256, 0, stream>>>(w_qkv, wqkvb, 98304);
  k_cvt<<<dim3(128),  256, 0, stream>>>(w_proj, wprojb, 32768);

  k_gemm_bt<0><<<dim3(12, 128), 256, 0, stream>>>(xb, wqkvb, qkvb, nullptr, 16384, 1536, 512);

  k_corr<<<dim3(512), 256, 0, stream>>>(qkvb, corrI, corrU);
  k_vT<<<dim3(512), 256, 0, stream>>>(qkvb, vT);

  k_attn<<<dim3(128), 256, 0, stream>>>(corrU, corrI, vT, out_attn);

  k_gemm_bt<1><<<dim3(4, 128), 256, 0, stream>>>(out_attn, wprojb, d_out, b_proj, 16384, 512, 512);
}

// Round 4
// 236.362 us; speedup vs baseline: 1.0787x; 1.0787x over previous
//
#include <hip/hip_runtime.h>
#include <hip/hip_bf16.h>
#include <stdint.h>

// CostVolumeAttention2: B=2, N=8192, C=512, heads=8, hd=64, T=8, H=W=32, U=49.
// Linearized softmax: |M|<=49/64^2=0.012 -> exp(M)=1+M to 7e-5 rel accuracy.
// attn @ v collapses to rank-50:  num = A'^T (A' v),  den = A'^T (A' 1),
// where A' = corr with an appended ones-row (u=49), zero pad to 64 rows.
// q,k are L2-normalized IN-PLACE (scale 1/(8*norm)) so corr = qn.kn directly.

#define DEVFN __device__ __forceinline__

typedef __attribute__((ext_vector_type(8))) short bf16x8;
typedef __attribute__((ext_vector_type(4))) short s16x4;
typedef __attribute__((ext_vector_type(4))) float f32x4;

DEVFN float bf2f(short s) {
  union { unsigned int u; float f; } v;
  v.u = ((unsigned int)(unsigned short)s) << 16;
  return v.f;
}
DEVFN short f2bf(float f) {
  __hip_bfloat16 h = __float2bfloat16(f);
  return *reinterpret_cast<short*>(&h);
}

DEVFN void gl_lds16(const void* g, void* l) {
  __builtin_amdgcn_global_load_lds((const __attribute__((address_space(1))) void*)g,
                                   (__attribute__((address_space(3))) void*)l, 16, 0, 0);
}

#define MFMA(a, b, c) __builtin_amdgcn_mfma_f32_16x16x32_bf16((a), (b), (c), 0, 0, 0)

#define NTOK 8192
#define HW   1024

// ---------------------------------------------------------------- fp32->bf16
__global__ void k_cvt(const float* __restrict__ in, short* __restrict__ out, int n8) {
  int i = blockIdx.x * blockDim.x + threadIdx.x;
  if (i >= n8) return;
  const float4* p = (const float4*)in + (size_t)i * 2;
  float4 a = p[0], b = p[1];
  bf16x8 r;
  r[0]=f2bf(a.x); r[1]=f2bf(a.y); r[2]=f2bf(a.z); r[3]=f2bf(a.w);
  r[4]=f2bf(b.x); r[5]=f2bf(b.y); r[6]=f2bf(b.z); r[7]=f2bf(b.w);
  *(bf16x8*)(out + (size_t)i * 8) = r;
}

// ------------------------------------------------- GEMM: C[M][N] = A * B^T
template<int F32OUT>
__global__ __launch_bounds__(256, 2) void k_gemm_bt(
    const short* __restrict__ A, const short* __restrict__ Bm,
    void* __restrict__ Cp, const float* __restrict__ bias, int M, int N, int K)
{
  __shared__ short lA[128 * 64];
  __shared__ short lB[128 * 64];
  const int tid = threadIdx.x;
  const int lane = tid & 63, w = tid >> 6;
  const int wm = w >> 1, wn = w & 1;
  const int r15 = lane & 15, hi = (lane >> 4) * 16, g4 = (lane >> 4) * 4;
  const int m0 = blockIdx.y * 128, n0 = blockIdx.x * 128;

  f32x4 acc[4][4];
#pragma unroll
  for (int i = 0; i < 4; i++)
#pragma unroll
    for (int j = 0; j < 4; j++) acc[i][j] = (f32x4)0.f;

  for (int k0 = 0; k0 < K; k0 += 64) {
#pragma unroll
    for (int it = 0; it < 4; it++) {
      int chunk = it * 256 + tid;
      int row = chunk >> 3;
      int sb = ((chunk & 7) * 16) ^ ((row & 7) << 4);
      const char* srcA = (const char*)(A + (size_t)(m0 + row) * K + k0) + sb;
      const char* srcB = (const char*)(Bm + (size_t)(n0 + row) * K + k0) + sb;
      short* dA = lA + (it * 256 + w * 64) * 8;
      short* dB = lB + (it * 256 + w * 64) * 8;
      gl_lds16(srcA, dA);
      gl_lds16(srcB, dB);
    }
    asm volatile("s_waitcnt vmcnt(0)" ::: "memory");
    __syncthreads();

    bf16x8 af[4][2], bfr[4][2];
#pragma unroll
    for (int mt = 0; mt < 4; mt++) {
      int row = wm * 64 + mt * 16 + r15;
#pragma unroll
      for (int kh = 0; kh < 2; kh++) {
        int off = row * 128 + ((kh * 64 + hi) ^ ((row & 7) << 4));
        af[mt][kh] = *(const bf16x8*)((const char*)lA + off);
      }
    }
#pragma unroll
    for (int nt = 0; nt < 4; nt++) {
      int row = wn * 64 + nt * 16 + r15;
#pragma unroll
      for (int kh = 0; kh < 2; kh++) {
        int off = row * 128 + ((kh * 64 + hi) ^ ((row & 7) << 4));
        bfr[nt][kh] = *(const bf16x8*)((const char*)lB + off);
      }
    }
#pragma unroll
    for (int mt = 0; mt < 4; mt++)
#pragma unroll
      for (int nt = 0; nt < 4; nt++) {
        acc[mt][nt] = MFMA(af[mt][0], bfr[nt][0], acc[mt][nt]);
        acc[mt][nt] = MFMA(af[mt][1], bfr[nt][1], acc[mt][nt]);
      }
    __syncthreads();
  }

#pragma unroll
  for (int mt = 0; mt < 4; mt++)
#pragma unroll
    for (int j = 0; j < 4; j++) {
      int row = m0 + wm * 64 + mt * 16 + g4 + j;
#pragma unroll
      for (int nt = 0; nt < 4; nt++) {
        int col = n0 + wn * 64 + nt * 16 + r15;
        float v = acc[mt][nt][j];
        if (F32OUT) ((float*)Cp)[(size_t)row * N + col] = v + bias[col];
        else        ((short*)Cp)[(size_t)row * N + col] = f2bf(v);
      }
    }
}

// ------------------------------------ in-place L2-normalize q,k (scale 1/(8n))
// unit = one (b,t,i,h) 64-dim vector = 128B; wave handles 8 units (1KB coalesced)
__global__ __launch_bounds__(256, 4) void k_norm(short* __restrict__ qkvb) {
  const int tid = threadIdx.x;
#pragma unroll 1
  for (int pass = 0; pass < 8; ++pass) {
    int uid = blockIdx.x * 256 + pass * 32 + (tid >> 3);
    int slice = uid >> 17;                  // 0: q (col 0), 1: k (col 512)
    int v = uid & 131071;                   // b|t|i|h = 1+3+10+3 bits
    int b = v >> 16, t = (v >> 13) & 7, i = (v >> 3) & 1023, h = v & 7;
    size_t addr = ((size_t)(b * NTOK + t * HW + i)) * 1536 + slice * 512 + h * 64 + (tid & 7) * 8;
    bf16x8 d = *(const bf16x8*)(qkvb + addr);
    float ss = 0.f;
#pragma unroll
    for (int e = 0; e < 8; e++) { float f = bf2f(d[e]); ss += f * f; }
    ss += __shfl_xor(ss, 1); ss += __shfl_xor(ss, 2); ss += __shfl_xor(ss, 4);
    float sc = 1.f / (8.f * fmaxf(sqrtf(ss), 1e-12f));
    bf16x8 o;
#pragma unroll
    for (int e = 0; e < 8; e++) o[e] = f2bf(bf2f(d[e]) * sc);
    *(bf16x8*)(qkvb + addr) = o;
  }
}

// ---------------------------------------------------------------- cost volume
// One WG per (bht, y). Gram qn_row(32px) x kn_rows(7x32px) via MFMA on
// pre-normalized bf16. Branch-free epilogue: dump all 28 tiles to bf16 LDS
// scratch, then 2 gather passes -> coalesced b128 global stores.
__global__ __launch_bounds__(256, 3) void k_corr(
    const short* __restrict__ qkvb, short* __restrict__ corrI, short* __restrict__ corrU)
{
  __shared__ short lq[32 * 64];     // 4KB: q row, swizzled 128B rows
  __shared__ short lk[224 * 64];    // 28KB: k rows p = dy*32+xx
  __shared__ short scr[28 * 256];   // 14KB: tile t -> [col p&15][row x&15]

  const int tid = threadIdx.x;
  const int lane = tid & 63, w = tid >> 6;
  const int r15 = lane & 15, hi = (lane >> 4) * 16, g4 = (lane >> 4) * 4;
  const int y = blockIdx.x & 31, bht = blockIdx.x >> 5;
  const int b = bht >> 6, head = (bht >> 3) & 7, tf = bht & 7;
  const int tk = (tf < 7) ? tf + 1 : 7;

  { // stage q: 32 rows x 128B = 256 chunks (1/thread)
    int row = tid >> 3;
    int sb = ((tid & 7) * 16) ^ ((row & 7) << 4);
    const char* src = (const char*)(qkvb + ((size_t)b * NTOK + tf * HW + y * 32 + row) * 1536 + head * 64) + sb;
    gl_lds16(src, lq + (w * 64) * 8);
  }
#pragma unroll
  for (int it = 0; it < 7; it++) { // stage k: 224 rows = 1792 chunks (7/thread)
    int chunk = it * 256 + tid;
    int row = chunk >> 3;          // p = dy*32+xx
    int dy = row >> 5, xx = row & 31;
    int ysrc = y + dy - 3;
    int sb = ((chunk & 7) * 16) ^ ((row & 7) << 4);
    if (ysrc >= 0 && ysrc < 32) {
      const char* src = (const char*)(qkvb + ((size_t)b * NTOK + tk * HW + ysrc * 32 + xx) * 1536 + 512 + head * 64) + sb;
      gl_lds16(src, lk + (it * 256 + w * 64) * 8);
    } else {
      *(bf16x8*)(lk + (size_t)chunk * 8) = (bf16x8)(short)0;
    }
  }
  asm volatile("s_waitcnt vmcnt(0)" ::: "memory");
  __syncthreads();

  // MFMA: 2 m-tiles x 14 n-tiles; wave w owns tiles t = w*7 .. w*7+6
  bf16x8 aq[2][2];
#pragma unroll
  for (int mt = 0; mt < 2; mt++) {
    int row = mt * 16 + r15;
#pragma unroll
    for (int kh = 0; kh < 2; kh++) {
      int off = row * 128 + ((kh * 64 + hi) ^ ((row & 7) << 4));
      aq[mt][kh] = *(const bf16x8*)((const char*)lq + off);
    }
  }
#pragma unroll
  for (int c = 0; c < 7; c++) {
    int t = w * 7 + c, mt = t & 1, nt = t >> 1;
    int rowB = nt * 16 + r15;
    f32x4 a = (f32x4)0.f;
#pragma unroll
    for (int kh = 0; kh < 2; kh++) {
      int off = rowB * 128 + ((kh * 64 + hi) ^ ((rowB & 7) << 4));
      bf16x8 bb = *(const bf16x8*)((const char*)lk + off);
      a = MFMA(aq[mt][kh], bb, a);
    }
    // dump tile to scratch: rows g4..g4+3 at col r15 (branch-free, b64)
    s16x4 pk;
    pk[0] = f2bf(a[0]); pk[1] = f2bf(a[1]); pk[2] = f2bf(a[2]); pk[3] = f2bf(a[3]);
    *(s16x4*)(scr + t * 256 + r15 * 16 + g4) = pk;
  }
  __syncthreads();

  { // gather corrI: thread -> (x, u0=8-group); contiguous 16B store
    int x = tid >> 3, u0 = (tid & 7) * 8;
    bf16x8 o;
#pragma unroll
    for (int e = 0; e < 8; e++) {
      int u = u0 + e;
      int dy = (u * 9363) >> 16;           // u/7 for u<64
      int dx = u - dy * 7;
      int xx = x + dx - 3;
      int xxc = min(max(xx, 0), 31);
      int t2 = ((min(dy, 6) * 2 + (xxc >> 4)) * 2 + (x >> 4));
      short vv = scr[t2 * 256 + (xxc & 15) * 16 + (x & 15)];
      vv = (xx == xxc && u < 49) ? vv : (short)0;
      o[e] = (u == 49) ? (short)0x3F80 : vv;   // ones row
    }
    *(bf16x8*)(corrI + ((size_t)bht * HW + y * 32 + x) * 64 + u0) = o;
  }
  { // gather corrU: thread -> (u, x0=8-group)
    int u = tid >> 2, x0 = (tid & 3) * 8;
    int dy = (u * 9363) >> 16;
    int dx = u - dy * 7;
    int dyc = min(dy, 6);
    bf16x8 o;
#pragma unroll
    for (int e = 0; e < 8; e++) {
      int x = x0 + e;
      int xx = x + dx - 3;
      int xxc = min(max(xx, 0), 31);
      int t2 = ((dyc * 2 + (xxc >> 4)) * 2 + (x >> 4));
      short vv = scr[t2 * 256 + (xxc & 15) * 16 + (x & 15)];
      vv = (xx == xxc && u < 49) ? vv : (short)0;
      o[e] = (u == 49) ? (short)0x3F80 : vv;
    }
    *(bf16x8*)(corrU + (size_t)bht * 65536 + u * HW + y * 32 + x0) = o;
  }
}

// ----------------------------------------------- v transpose: vT[bht][d][i]
__global__ __launch_bounds__(256, 2) void k_vT(const short* __restrict__ qkvb, short* __restrict__ vT)
{
  __shared__ short lt[128 * 72];  // [i][d] pad 72
  const int tid = threadIdx.x;
  const int bht = blockIdx.x >> 2;
  const int cbase = (blockIdx.x & 3) * 256;
  const int b = bht >> 6, head = (bht >> 3) & 7, tf = bht & 7;
  const size_t rowbase = ((size_t)b * NTOK + tf * HW) * 1536 + 1024 + head * 64;
  for (int c0 = cbase; c0 < cbase + 256; c0 += 128) {
    __syncthreads();
#pragma unroll
    for (int it = 0; it < 4; it++) {
      int idx = it * 256 + tid;
      int row = idx >> 3, part = idx & 7;
      bf16x8 v = *(const bf16x8*)(qkvb + rowbase + (size_t)(c0 + row) * 1536 + part * 8);
      *(bf16x8*)(lt + row * 72 + part * 8) = v;
    }
    __syncthreads();
    int d = tid & 63, blk = tid >> 6;
#pragma unroll
    for (int qq = 0; qq < 4; qq++) {
      bf16x8 o;
#pragma unroll
      for (int e = 0; e < 8; e++) o[e] = lt[(blk * 32 + qq * 8 + e) * 72 + d];
      *(bf16x8*)(vT + ((size_t)bht * 64 + d) * HW + c0 + blk * 32 + qq * 8) = o;
    }
  }
}

// --------------------------------- fused rank-50 attention, one WG per bht
__global__ __launch_bounds__(256, 2) void k_attn(
    const short* __restrict__ corrU, const short* __restrict__ corrI,
    const short* __restrict__ vT, short* __restrict__ out_attn)
{
  __shared__ short lV[64 * 64];
  __shared__ short lU[64 * 64];
  __shared__ short GTl[64 * 72];
  __shared__ float cl[64];
  __shared__ float cpart[256];
  const int tid = threadIdx.x, lane = tid & 63, w = tid >> 6;
  const int r15 = lane & 15, hi = (lane >> 4) * 16, g4 = (lane >> 4) * 4, g8 = (lane >> 4) * 8;
  const int bht = blockIdx.x;
  const int b = bht >> 6, head = (bht >> 3) & 7, tf = bht & 7;

  f32x4 accP[4];
#pragma unroll
  for (int nt = 0; nt < 4; nt++) accP[nt] = (f32x4)0.f;
  float c1p = 0.f;
  const short* vbase = vT + (size_t)bht * 64 * HW;
  const short* ubase = corrU + (size_t)bht * 65536;

  for (int i0 = 0; i0 < 1024; i0 += 64) {
#pragma unroll
    for (int it = 0; it < 2; it++) {
      int chunk = it * 256 + tid;
      int row = chunk >> 3;
      int sb = ((chunk & 7) * 16) ^ ((row & 7) << 4);
      gl_lds16((const char*)(vbase + (size_t)row * HW + i0) + sb, lV + (it * 256 + w * 64) * 8);
      gl_lds16((const char*)(ubase + (size_t)row * HW + i0) + sb, lU + (it * 256 + w * 64) * 8);
    }
    asm volatile("s_waitcnt vmcnt(0)" ::: "memory");
    __syncthreads();
    bf16x8 av[2];
    int rowA = w * 16 + r15;
#pragma unroll
    for (int kh = 0; kh < 2; kh++) {
      int off = rowA * 128 + ((kh * 64 + hi) ^ ((rowA & 7) << 4));
      av[kh] = *(const bf16x8*)((const char*)lV + off);
    }
#pragma unroll
    for (int nt = 0; nt < 4; nt++) {
      int rowB = nt * 16 + r15;
#pragma unroll
      for (int kh = 0; kh < 2; kh++) {
        int off = rowB * 128 + ((kh * 64 + hi) ^ ((rowB & 7) << 4));
        bf16x8 bu = *(const bf16x8*)((const char*)lU + off);
        accP[nt] = MFMA(av[kh], bu, accP[nt]);
      }
    }
    { // c1 partials
      int u = tid >> 2, partc = tid & 3;
#pragma unroll
      for (int h = 0; h < 2; h++) {
        int off = u * 128 + ((partc * 32 + h * 16) ^ ((u & 7) << 4));
        bf16x8 vv = *(const bf16x8*)((const char*)lU + off);
#pragma unroll
        for (int e = 0; e < 8; e++) c1p += bf2f(vv[e]);
      }
    }
    __syncthreads();
  }
  cpart[tid] = c1p;
#pragma unroll
  for (int nt = 0; nt < 4; nt++)
#pragma unroll
    for (int j = 0; j < 4; j++) {
      int d = w * 16 + g4 + j, u = nt * 16 + r15;
      GTl[d * 72 + u] = f2bf(accP[nt][j]);
    }
  __syncthreads();
  if (tid < 64) cl[tid] = cpart[4 * tid] + cpart[4 * tid + 1] + cpart[4 * tid + 2] + cpart[4 * tid + 3];
  __syncthreads();

  bf16x8 gtb[4][2];
#pragma unroll
  for (int nt = 0; nt < 4; nt++)
#pragma unroll
    for (int kh = 0; kh < 2; kh++)
      gtb[nt][kh] = *(const bf16x8*)((const char*)GTl + (nt * 16 + r15) * 144 + kh * 64 + hi);

  float c1r[2][8];
#pragma unroll
  for (int kh = 0; kh < 2; kh++)
#pragma unroll
    for (int e = 0; e < 8; e++) c1r[kh][e] = cl[kh * 32 + g8 + e];

  const short* ibase = corrI + (size_t)bht * HW * 64;
  for (int s = 0; s < 16; s++) {
    int i0 = w * 256 + s * 16;
    bf16x8 af[2];
#pragma unroll
    for (int kh = 0; kh < 2; kh++)
      af[kh] = *(const bf16x8*)(ibase + (size_t)(i0 + r15) * 64 + kh * 32 + g8);
    f32x4 a2[4];
#pragma unroll
    for (int nt = 0; nt < 4; nt++) a2[nt] = (f32x4)0.f;
#pragma unroll
    for (int nt = 0; nt < 4; nt++)
#pragma unroll
      for (int kh = 0; kh < 2; kh++) a2[nt] = MFMA(af[kh], gtb[nt][kh], a2[nt]);

    float dp = 0.f;
#pragma unroll
    for (int kh = 0; kh < 2; kh++)
#pragma unroll
      for (int e = 0; e < 8; e++) dp += bf2f(af[kh][e]) * c1r[kh][e];
    dp += __shfl_xor(dp, 16);
    dp += __shfl_xor(dp, 32);

#pragma unroll
    for (int j = 0; j < 4; j++) {
      float dj = __shfl(dp, g4 + j);
      float inv = 1.f / dj;
      int i = i0 + g4 + j;
      size_t outrow = ((size_t)b * NTOK + tf * HW + i) * 512 + head * 64;
#pragma unroll
      for (int nt = 0; nt < 4; nt++)
        out_attn[outrow + nt * 16 + r15] = f2bf(a2[nt][j] * inv);
    }
  }
}

extern "C" void kernel_launch(void* const* d_in, const int* in_sizes, int n_in,
                              void* d_out, int out_size, void* d_ws, size_t ws_size,
                              hipStream_t stream) {
  (void)in_sizes; (void)n_in; (void)out_size; (void)ws_size;
  const float* x      = (const float*)d_in[0];
  const float* w_qkv  = (const float*)d_in[1];
  const float* w_proj = (const float*)d_in[2];
  const float* b_proj = (const float*)d_in[3];

  char* ws = (char*)d_ws;
  short* qkvb   = (short*)(ws);                 // 50,331,648 B [16384][1536]
  short* xb     = (short*)(ws + 50331648);      // 16,777,216 B
  short* corrU  = (short*)(ws + 67108864);      // 16,777,216 B [128][64][1024]
  short* vT     = (short*)(ws + 83886080);      // 16,777,216 B [128][64][1024]
  short* wqkvb  = (short*)(ws + 100663296);     //  1,572,864 B
  short* wprojb = (short*)(ws + 102236160);     //    524,288 B
  short* corrI    = xb;    // alias: xb dead after qkv GEMM
  short* out_attn = qkvb;  // alias: qkvb dead after corr + vT

  k_cvt<<<dim3(4096), 256, 0, stream>>>(x, xb, 1048576);
  k_cvt<<<dim3(384),  256, 0, stream>>>(w_qkv, wqkvb, 98304);
  k_cvt<<<dim3(128),  256, 0, stream>>>(w_proj, wprojb, 32768);

  k_gemm_bt<0><<<dim3(12, 128), 256, 0, stream>>>(xb, wqkvb, qkvb, nullptr, 16384, 1536, 512);

  k_norm<<<dim3(1024), 256, 0, stream>>>(qkvb);

  k_corr<<<dim3(4096), 256, 0, stream>>>(qkvb, corrI, corrU);
  k_vT<<<dim3(512), 256, 0, stream>>>(qkvb, vT);

  k_attn<<<dim3(128), 256, 0, stream>>>(corrU, corrI, vT, out_attn);

  k_gemm_bt<1><<<dim3(4, 128), 256, 0, stream>>>(out_attn, wprojb, d_out, b_proj, 16384, 512, 512);
}

// Round 5
// 230.032 us; speedup vs baseline: 1.1084x; 1.0275x over previous
//
#include <hip/hip_runtime.h>
#include <hip/hip_bf16.h>
#include <stdint.h>

// CostVolumeAttention2: B=2, N=8192, C=512, heads=8, hd=64, T=8, H=W=32, U=49.
// Linearized softmax: |M|<=49/64^2=0.012 -> exp(M)=1+M to 7e-5 rel accuracy.
// attn @ v collapses to rank-50:  num = A'^T (A' v),  den = A'^T (A' 1),
// where A' = corr with an appended ones-row (u=49), zero pad to 64 rows.
// q,k are L2-normalized IN-PLACE (scale 1/(8*norm)) so corr = qn.kn directly.
// R5: XCD-locality block swizzles (k_corr: bht%8==pid%8 so the k-row window
// is served by one XCD's L2; GEMMs: 16 m-panels per XCD).

#define DEVFN __device__ __forceinline__

typedef __attribute__((ext_vector_type(8))) short bf16x8;
typedef __attribute__((ext_vector_type(4))) short s16x4;
typedef __attribute__((ext_vector_type(4))) float f32x4;

DEVFN float bf2f(short s) {
  union { unsigned int u; float f; } v;
  v.u = ((unsigned int)(unsigned short)s) << 16;
  return v.f;
}
DEVFN short f2bf(float f) {
  __hip_bfloat16 h = __float2bfloat16(f);
  return *reinterpret_cast<short*>(&h);
}

DEVFN void gl_lds16(const void* g, void* l) {
  __builtin_amdgcn_global_load_lds((const __attribute__((address_space(1))) void*)g,
                                   (__attribute__((address_space(3))) void*)l, 16, 0, 0);
}

#define MFMA(a, b, c) __builtin_amdgcn_mfma_f32_16x16x32_bf16((a), (b), (c), 0, 0, 0)

#define NTOK 8192
#define HW   1024

// ---------------------------------------------------------------- fp32->bf16
__global__ void k_cvt(const float* __restrict__ in, short* __restrict__ out, int n8) {
  int i = blockIdx.x * blockDim.x + threadIdx.x;
  if (i >= n8) return;
  const float4* p = (const float4*)in + (size_t)i * 2;
  float4 a = p[0], b = p[1];
  bf16x8 r;
  r[0]=f2bf(a.x); r[1]=f2bf(a.y); r[2]=f2bf(a.z); r[3]=f2bf(a.w);
  r[4]=f2bf(b.x); r[5]=f2bf(b.y); r[6]=f2bf(b.z); r[7]=f2bf(b.w);
  *(bf16x8*)(out + (size_t)i * 8) = r;
}

// ------------------------------------------------- GEMM: C[M][N] = A * B^T
// 1D grid = 128*nblocks; decode keeps 16 consecutive m-panels on one XCD so
// A-panels (16x128KB=2MB) stay L2-resident. Requires M==16384 (128 m-blocks).
template<int F32OUT>
__global__ __launch_bounds__(256, 2) void k_gemm_bt(
    const short* __restrict__ A, const short* __restrict__ Bm,
    void* __restrict__ Cp, const float* __restrict__ bias, int M, int N, int K)
{
  __shared__ short lA[128 * 64];
  __shared__ short lB[128 * 64];
  const int tid = threadIdx.x;
  const int lane = tid & 63, w = tid >> 6;
  const int wm = w >> 1, wn = w & 1;
  const int r15 = lane & 15, hi = (lane >> 4) * 16, g4 = (lane >> 4) * 4;
  const int pid = blockIdx.x;
  const int m0 = ((pid & 7) * 16 + ((pid >> 3) & 15)) * 128;
  const int n0 = (pid >> 7) * 128;

  f32x4 acc[4][4];
#pragma unroll
  for (int i = 0; i < 4; i++)
#pragma unroll
    for (int j = 0; j < 4; j++) acc[i][j] = (f32x4)0.f;

  for (int k0 = 0; k0 < K; k0 += 64) {
#pragma unroll
    for (int it = 0; it < 4; it++) {
      int chunk = it * 256 + tid;
      int row = chunk >> 3;
      int sb = ((chunk & 7) * 16) ^ ((row & 7) << 4);
      const char* srcA = (const char*)(A + (size_t)(m0 + row) * K + k0) + sb;
      const char* srcB = (const char*)(Bm + (size_t)(n0 + row) * K + k0) + sb;
      short* dA = lA + (it * 256 + w * 64) * 8;
      short* dB = lB + (it * 256 + w * 64) * 8;
      gl_lds16(srcA, dA);
      gl_lds16(srcB, dB);
    }
    asm volatile("s_waitcnt vmcnt(0)" ::: "memory");
    __syncthreads();

    bf16x8 af[4][2], bfr[4][2];
#pragma unroll
    for (int mt = 0; mt < 4; mt++) {
      int row = wm * 64 + mt * 16 + r15;
#pragma unroll
      for (int kh = 0; kh < 2; kh++) {
        int off = row * 128 + ((kh * 64 + hi) ^ ((row & 7) << 4));
        af[mt][kh] = *(const bf16x8*)((const char*)lA + off);
      }
    }
#pragma unroll
    for (int nt = 0; nt < 4; nt++) {
      int row = wn * 64 + nt * 16 + r15;
#pragma unroll
      for (int kh = 0; kh < 2; kh++) {
        int off = row * 128 + ((kh * 64 + hi) ^ ((row & 7) << 4));
        bfr[nt][kh] = *(const bf16x8*)((const char*)lB + off);
      }
    }
#pragma unroll
    for (int mt = 0; mt < 4; mt++)
#pragma unroll
      for (int nt = 0; nt < 4; nt++) {
        acc[mt][nt] = MFMA(af[mt][0], bfr[nt][0], acc[mt][nt]);
        acc[mt][nt] = MFMA(af[mt][1], bfr[nt][1], acc[mt][nt]);
      }
    __syncthreads();
  }

#pragma unroll
  for (int mt = 0; mt < 4; mt++)
#pragma unroll
    for (int j = 0; j < 4; j++) {
      int row = m0 + wm * 64 + mt * 16 + g4 + j;
#pragma unroll
      for (int nt = 0; nt < 4; nt++) {
        int col = n0 + wn * 64 + nt * 16 + r15;
        float v = acc[mt][nt][j];
        if (F32OUT) ((float*)Cp)[(size_t)row * N + col] = v + bias[col];
        else        ((short*)Cp)[(size_t)row * N + col] = f2bf(v);
      }
    }
}

// ------------------------------------ in-place L2-normalize q,k (scale 1/(8n))
__global__ __launch_bounds__(256, 4) void k_norm(short* __restrict__ qkvb) {
  const int tid = threadIdx.x;
#pragma unroll 1
  for (int pass = 0; pass < 8; ++pass) {
    int uid = blockIdx.x * 256 + pass * 32 + (tid >> 3);
    int slice = uid >> 17;                  // 0: q (col 0), 1: k (col 512)
    int v = uid & 131071;                   // b|t|i|h = 1+3+10+3 bits
    int b = v >> 16, t = (v >> 13) & 7, i = (v >> 3) & 1023, h = v & 7;
    size_t addr = ((size_t)(b * NTOK + t * HW + i)) * 1536 + slice * 512 + h * 64 + (tid & 7) * 8;
    bf16x8 d = *(const bf16x8*)(qkvb + addr);
    float ss = 0.f;
#pragma unroll
    for (int e = 0; e < 8; e++) { float f = bf2f(d[e]); ss += f * f; }
    ss += __shfl_xor(ss, 1); ss += __shfl_xor(ss, 2); ss += __shfl_xor(ss, 4);
    float sc = 1.f / (8.f * fmaxf(sqrtf(ss), 1e-12f));
    bf16x8 o;
#pragma unroll
    for (int e = 0; e < 8; e++) o[e] = f2bf(bf2f(d[e]) * sc);
    *(bf16x8*)(qkvb + addr) = o;
  }
}

// ---------------------------------------------------------------- cost volume
// One WG per (bht, y), XCD-locality decode: bht%8 == pid%8 so same-bht
// neighbor y-blocks (sharing 6/7 k rows) run on the same XCD -> L2 hits.
__global__ __launch_bounds__(256, 3) void k_corr(
    const short* __restrict__ qkvb, short* __restrict__ corrI, short* __restrict__ corrU)
{
  __shared__ short lq[32 * 64];     // 4KB: q row, swizzled 128B rows
  __shared__ short lk[224 * 64];    // 28KB: k rows p = dy*32+xx
  __shared__ short scr[28 * 256];   // 14KB: tile t -> [col p&15][row x&15]

  const int tid = threadIdx.x;
  const int lane = tid & 63, w = tid >> 6;
  const int r15 = lane & 15, hi = (lane >> 4) * 16, g4 = (lane >> 4) * 4;
  const int pid = blockIdx.x;
  const int bht = (pid & 7) + 8 * ((pid >> 3) & 15);   // 16 bht per XCD
  const int y = pid >> 7;                              // y sweeps per XCD
  const int b = bht >> 6, head = (bht >> 3) & 7, tf = bht & 7;
  const int tk = (tf < 7) ? tf + 1 : 7;

  { // stage q: 32 rows x 128B = 256 chunks (1/thread)
    int row = tid >> 3;
    int sb = ((tid & 7) * 16) ^ ((row & 7) << 4);
    const char* src = (const char*)(qkvb + ((size_t)b * NTOK + tf * HW + y * 32 + row) * 1536 + head * 64) + sb;
    gl_lds16(src, lq + (w * 64) * 8);
  }
#pragma unroll
  for (int it = 0; it < 7; it++) { // stage k: 224 rows = 1792 chunks (7/thread)
    int chunk = it * 256 + tid;
    int row = chunk >> 3;          // p = dy*32+xx
    int dy = row >> 5, xx = row & 31;
    int ysrc = y + dy - 3;
    int sb = ((chunk & 7) * 16) ^ ((row & 7) << 4);
    if (ysrc >= 0 && ysrc < 32) {
      const char* src = (const char*)(qkvb + ((size_t)b * NTOK + tk * HW + ysrc * 32 + xx) * 1536 + 512 + head * 64) + sb;
      gl_lds16(src, lk + (it * 256 + w * 64) * 8);
    } else {
      *(bf16x8*)(lk + (size_t)chunk * 8) = (bf16x8)(short)0;
    }
  }
  asm volatile("s_waitcnt vmcnt(0)" ::: "memory");
  __syncthreads();

  // MFMA: 2 m-tiles x 14 n-tiles; wave w owns tiles t = w*7 .. w*7+6
  bf16x8 aq[2][2];
#pragma unroll
  for (int mt = 0; mt < 2; mt++) {
    int row = mt * 16 + r15;
#pragma unroll
    for (int kh = 0; kh < 2; kh++) {
      int off = row * 128 + ((kh * 64 + hi) ^ ((row & 7) << 4));
      aq[mt][kh] = *(const bf16x8*)((const char*)lq + off);
    }
  }
#pragma unroll
  for (int c = 0; c < 7; c++) {
    int t = w * 7 + c, mt = t & 1, nt = t >> 1;
    int rowB = nt * 16 + r15;
    f32x4 a = (f32x4)0.f;
#pragma unroll
    for (int kh = 0; kh < 2; kh++) {
      int off = rowB * 128 + ((kh * 64 + hi) ^ ((rowB & 7) << 4));
      bf16x8 bb = *(const bf16x8*)((const char*)lk + off);
      a = MFMA(aq[mt][kh], bb, a);
    }
    s16x4 pk;
    pk[0] = f2bf(a[0]); pk[1] = f2bf(a[1]); pk[2] = f2bf(a[2]); pk[3] = f2bf(a[3]);
    *(s16x4*)(scr + t * 256 + r15 * 16 + g4) = pk;
  }
  __syncthreads();

  { // gather corrI: thread -> (x, u0=8-group); contiguous 16B store
    int x = tid >> 3, u0 = (tid & 7) * 8;
    bf16x8 o;
#pragma unroll
    for (int e = 0; e < 8; e++) {
      int u = u0 + e;
      int dy = (u * 9363) >> 16;           // u/7 for u<64
      int dx = u - dy * 7;
      int xx = x + dx - 3;
      int xxc = min(max(xx, 0), 31);
      int t2 = ((min(dy, 6) * 2 + (xxc >> 4)) * 2 + (x >> 4));
      short vv = scr[t2 * 256 + (xxc & 15) * 16 + (x & 15)];
      vv = (xx == xxc && u < 49) ? vv : (short)0;
      o[e] = (u == 49) ? (short)0x3F80 : vv;   // ones row
    }
    *(bf16x8*)(corrI + ((size_t)bht * HW + y * 32 + x) * 64 + u0) = o;
  }
  { // gather corrU: thread -> (u, x0=8-group)
    int u = tid >> 2, x0 = (tid & 3) * 8;
    int dy = (u * 9363) >> 16;
    int dx = u - dy * 7;
    int dyc = min(dy, 6);
    bf16x8 o;
#pragma unroll
    for (int e = 0; e < 8; e++) {
      int x = x0 + e;
      int xx = x + dx - 3;
      int xxc = min(max(xx, 0), 31);
      int t2 = ((dyc * 2 + (xxc >> 4)) * 2 + (x >> 4));
      short vv = scr[t2 * 256 + (xxc & 15) * 16 + (x & 15)];
      vv = (xx == xxc && u < 49) ? vv : (short)0;
      o[e] = (u == 49) ? (short)0x3F80 : vv;
    }
    *(bf16x8*)(corrU + (size_t)bht * 65536 + u * HW + y * 32 + x0) = o;
  }
}

// ----------------------------------------------- v transpose: vT[bht][d][i]
__global__ __launch_bounds__(256, 2) void k_vT(const short* __restrict__ qkvb, short* __restrict__ vT)
{
  __shared__ short lt[128 * 72];  // [i][d] pad 72
  const int tid = threadIdx.x;
  const int bht = blockIdx.x >> 2;
  const int cbase = (blockIdx.x & 3) * 256;
  const int b = bht >> 6, head = (bht >> 3) & 7, tf = bht & 7;
  const size_t rowbase = ((size_t)b * NTOK + tf * HW) * 1536 + 1024 + head * 64;
  for (int c0 = cbase; c0 < cbase + 256; c0 += 128) {
    __syncthreads();
#pragma unroll
    for (int it = 0; it < 4; it++) {
      int idx = it * 256 + tid;
      int row = idx >> 3, part = idx & 7;
      bf16x8 v = *(const bf16x8*)(qkvb + rowbase + (size_t)(c0 + row) * 1536 + part * 8);
      *(bf16x8*)(lt + row * 72 + part * 8) = v;
    }
    __syncthreads();
    int d = tid & 63, blk = tid >> 6;
#pragma unroll
    for (int qq = 0; qq < 4; qq++) {
      bf16x8 o;
#pragma unroll
      for (int e = 0; e < 8; e++) o[e] = lt[(blk * 32 + qq * 8 + e) * 72 + d];
      *(bf16x8*)(vT + ((size_t)bht * 64 + d) * HW + c0 + blk * 32 + qq * 8) = o;
    }
  }
}

// --------------------------------- fused rank-50 attention, one WG per bht
__global__ __launch_bounds__(256, 2) void k_attn(
    const short* __restrict__ corrU, const short* __restrict__ corrI,
    const short* __restrict__ vT, short* __restrict__ out_attn)
{
  __shared__ short lV[64 * 64];
  __shared__ short lU[64 * 64];
  __shared__ short GTl[64 * 72];
  __shared__ float cl[64];
  __shared__ float cpart[256];
  const int tid = threadIdx.x, lane = tid & 63, w = tid >> 6;
  const int r15 = lane & 15, hi = (lane >> 4) * 16, g4 = (lane >> 4) * 4, g8 = (lane >> 4) * 8;
  const int bht = blockIdx.x;
  const int b = bht >> 6, head = (bht >> 3) & 7, tf = bht & 7;

  f32x4 accP[4];
#pragma unroll
  for (int nt = 0; nt < 4; nt++) accP[nt] = (f32x4)0.f;
  float c1p = 0.f;
  const short* vbase = vT + (size_t)bht * 64 * HW;
  const short* ubase = corrU + (size_t)bht * 65536;

  for (int i0 = 0; i0 < 1024; i0 += 64) {
#pragma unroll
    for (int it = 0; it < 2; it++) {
      int chunk = it * 256 + tid;
      int row = chunk >> 3;
      int sb = ((chunk & 7) * 16) ^ ((row & 7) << 4);
      gl_lds16((const char*)(vbase + (size_t)row * HW + i0) + sb, lV + (it * 256 + w * 64) * 8);
      gl_lds16((const char*)(ubase + (size_t)row * HW + i0) + sb, lU + (it * 256 + w * 64) * 8);
    }
    asm volatile("s_waitcnt vmcnt(0)" ::: "memory");
    __syncthreads();
    bf16x8 av[2];
    int rowA = w * 16 + r15;
#pragma unroll
    for (int kh = 0; kh < 2; kh++) {
      int off = rowA * 128 + ((kh * 64 + hi) ^ ((rowA & 7) << 4));
      av[kh] = *(const bf16x8*)((const char*)lV + off);
    }
#pragma unroll
    for (int nt = 0; nt < 4; nt++) {
      int rowB = nt * 16 + r15;
#pragma unroll
      for (int kh = 0; kh < 2; kh++) {
        int off = rowB * 128 + ((kh * 64 + hi) ^ ((rowB & 7) << 4));
        bf16x8 bu = *(const bf16x8*)((const char*)lU + off);
        accP[nt] = MFMA(av[kh], bu, accP[nt]);
      }
    }
    { // c1 partials
      int u = tid >> 2, partc = tid & 3;
#pragma unroll
      for (int h = 0; h < 2; h++) {
        int off = u * 128 + ((partc * 32 + h * 16) ^ ((u & 7) << 4));
        bf16x8 vv = *(const bf16x8*)((const char*)lU + off);
#pragma unroll
        for (int e = 0; e < 8; e++) c1p += bf2f(vv[e]);
      }
    }
    __syncthreads();
  }
  cpart[tid] = c1p;
#pragma unroll
  for (int nt = 0; nt < 4; nt++)
#pragma unroll
    for (int j = 0; j < 4; j++) {
      int d = w * 16 + g4 + j, u = nt * 16 + r15;
      GTl[d * 72 + u] = f2bf(accP[nt][j]);
    }
  __syncthreads();
  if (tid < 64) cl[tid] = cpart[4 * tid] + cpart[4 * tid + 1] + cpart[4 * tid + 2] + cpart[4 * tid + 3];
  __syncthreads();

  bf16x8 gtb[4][2];
#pragma unroll
  for (int nt = 0; nt < 4; nt++)
#pragma unroll
    for (int kh = 0; kh < 2; kh++)
      gtb[nt][kh] = *(const bf16x8*)((const char*)GTl + (nt * 16 + r15) * 144 + kh * 64 + hi);

  float c1r[2][8];
#pragma unroll
  for (int kh = 0; kh < 2; kh++)
#pragma unroll
    for (int e = 0; e < 8; e++) c1r[kh][e] = cl[kh * 32 + g8 + e];

  const short* ibase = corrI + (size_t)bht * HW * 64;
  for (int s = 0; s < 16; s++) {
    int i0 = w * 256 + s * 16;
    bf16x8 af[2];
#pragma unroll
    for (int kh = 0; kh < 2; kh++)
      af[kh] = *(const bf16x8*)(ibase + (size_t)(i0 + r15) * 64 + kh * 32 + g8);
    f32x4 a2[4];
#pragma unroll
    for (int nt = 0; nt < 4; nt++) a2[nt] = (f32x4)0.f;
#pragma unroll
    for (int nt = 0; nt < 4; nt++)
#pragma unroll
      for (int kh = 0; kh < 2; kh++) a2[nt] = MFMA(af[kh], gtb[nt][kh], a2[nt]);

    float dp = 0.f;
#pragma unroll
    for (int kh = 0; kh < 2; kh++)
#pragma unroll
      for (int e = 0; e < 8; e++) dp += bf2f(af[kh][e]) * c1r[kh][e];
    dp += __shfl_xor(dp, 16);
    dp += __shfl_xor(dp, 32);

#pragma unroll
    for (int j = 0; j < 4; j++) {
      float dj = __shfl(dp, g4 + j);
      float inv = 1.f / dj;
      int i = i0 + g4 + j;
      size_t outrow = ((size_t)b * NTOK + tf * HW + i) * 512 + head * 64;
#pragma unroll
      for (int nt = 0; nt < 4; nt++)
        out_attn[outrow + nt * 16 + r15] = f2bf(a2[nt][j] * inv);
    }
  }
}

extern "C" void kernel_launch(void* const* d_in, const int* in_sizes, int n_in,
                              void* d_out, int out_size, void* d_ws, size_t ws_size,
                              hipStream_t stream) {
  (void)in_sizes; (void)n_in; (void)out_size; (void)ws_size;
  const float* x      = (const float*)d_in[0];
  const float* w_qkv  = (const float*)d_in[1];
  const float* w_proj = (const float*)d_in[2];
  const float* b_proj = (const float*)d_in[3];

  char* ws = (char*)d_ws;
  short* qkvb   = (short*)(ws);                 // 50,331,648 B [16384][1536]
  short* xb     = (short*)(ws + 50331648);      // 16,777,216 B
  short* corrU  = (short*)(ws + 67108864);      // 16,777,216 B [128][64][1024]
  short* vT     = (short*)(ws + 83886080);      // 16,777,216 B [128][64][1024]
  short* wqkvb  = (short*)(ws + 100663296);     //  1,572,864 B
  short* wprojb = (short*)(ws + 102236160);     //    524,288 B
  short* corrI    = xb;    // alias: xb dead after qkv GEMM
  short* out_attn = qkvb;  // alias: qkvb dead after corr + vT

  k_cvt<<<dim3(4096), 256, 0, stream>>>(x, xb, 1048576);
  k_cvt<<<dim3(384),  256, 0, stream>>>(w_qkv, wqkvb, 98304);
  k_cvt<<<dim3(128),  256, 0, stream>>>(w_proj, wprojb, 32768);

  k_gemm_bt<0><<<dim3(1536), 256, 0, stream>>>(xb, wqkvb, qkvb, nullptr, 16384, 1536, 512);

  k_norm<<<dim3(1024), 256, 0, stream>>>(qkvb);

  k_corr<<<dim3(4096), 256, 0, stream>>>(qkvb, corrI, corrU);
  k_vT<<<dim3(512), 256, 0, stream>>>(qkvb, vT);

  k_attn<<<dim3(128), 256, 0, stream>>>(corrU, corrI, vT, out_attn);

  k_gemm_bt<1><<<dim3(512), 256, 0, stream>>>(out_attn, wprojb, d_out, b_proj, 16384, 512, 512);
}

// Round 6
// 224.001 us; speedup vs baseline: 1.1382x; 1.0269x over previous
//
#include <hip/hip_runtime.h>
#include <hip/hip_bf16.h>
#include <stdint.h>

// CostVolumeAttention2: B=2, N=8192, C=512, heads=8, hd=64, T=8, H=W=32, U=49.
// Linearized softmax: |M|<=49/64^2=0.012 -> exp(M)=1+M to 7e-5 rel accuracy.
// attn @ v collapses to rank-50:  num = A'^T (A' v),  den = A'^T (A' 1),
// where A' = corr with an appended ones-row (u=49), zero pad to 64 rows.
// q,k are L2-normalized IN-PLACE (scale 1/(8*norm)) so corr = qn.kn directly.
// R6: occupancy push. k_corr LDS 46->32KB (scr aliased into lk after barrier,
// accs held in regs) -> 4-5 blocks/CU. k_attn d-split: 2 blocks/bht (grid 256).

#define DEVFN __device__ __forceinline__

typedef __attribute__((ext_vector_type(8))) short bf16x8;
typedef __attribute__((ext_vector_type(4))) short s16x4;
typedef __attribute__((ext_vector_type(4))) float f32x4;

DEVFN float bf2f(short s) {
  union { unsigned int u; float f; } v;
  v.u = ((unsigned int)(unsigned short)s) << 16;
  return v.f;
}
DEVFN short f2bf(float f) {
  __hip_bfloat16 h = __float2bfloat16(f);
  return *reinterpret_cast<short*>(&h);
}

DEVFN void gl_lds16(const void* g, void* l) {
  __builtin_amdgcn_global_load_lds((const __attribute__((address_space(1))) void*)g,
                                   (__attribute__((address_space(3))) void*)l, 16, 0, 0);
}

#define MFMA(a, b, c) __builtin_amdgcn_mfma_f32_16x16x32_bf16((a), (b), (c), 0, 0, 0)

#define NTOK 8192
#define HW   1024

// ---------------------------------------------------------------- fp32->bf16
__global__ void k_cvt(const float* __restrict__ in, short* __restrict__ out, int n8) {
  int i = blockIdx.x * blockDim.x + threadIdx.x;
  if (i >= n8) return;
  const float4* p = (const float4*)in + (size_t)i * 2;
  float4 a = p[0], b = p[1];
  bf16x8 r;
  r[0]=f2bf(a.x); r[1]=f2bf(a.y); r[2]=f2bf(a.z); r[3]=f2bf(a.w);
  r[4]=f2bf(b.x); r[5]=f2bf(b.y); r[6]=f2bf(b.z); r[7]=f2bf(b.w);
  *(bf16x8*)(out + (size_t)i * 8) = r;
}

// ------------------------------------------------- GEMM: C[M][N] = A * B^T
// 1D grid = 128*nblocks; 16 consecutive m-panels per XCD for L2 residency.
template<int F32OUT>
__global__ __launch_bounds__(256, 2) void k_gemm_bt(
    const short* __restrict__ A, const short* __restrict__ Bm,
    void* __restrict__ Cp, const float* __restrict__ bias, int M, int N, int K)
{
  __shared__ short lA[128 * 64];
  __shared__ short lB[128 * 64];
  const int tid = threadIdx.x;
  const int lane = tid & 63, w = tid >> 6;
  const int wm = w >> 1, wn = w & 1;
  const int r15 = lane & 15, hi = (lane >> 4) * 16, g4 = (lane >> 4) * 4;
  const int pid = blockIdx.x;
  const int m0 = ((pid & 7) * 16 + ((pid >> 3) & 15)) * 128;
  const int n0 = (pid >> 7) * 128;

  f32x4 acc[4][4];
#pragma unroll
  for (int i = 0; i < 4; i++)
#pragma unroll
    for (int j = 0; j < 4; j++) acc[i][j] = (f32x4)0.f;

  for (int k0 = 0; k0 < K; k0 += 64) {
#pragma unroll
    for (int it = 0; it < 4; it++) {
      int chunk = it * 256 + tid;
      int row = chunk >> 3;
      int sb = ((chunk & 7) * 16) ^ ((row & 7) << 4);
      const char* srcA = (const char*)(A + (size_t)(m0 + row) * K + k0) + sb;
      const char* srcB = (const char*)(Bm + (size_t)(n0 + row) * K + k0) + sb;
      short* dA = lA + (it * 256 + w * 64) * 8;
      short* dB = lB + (it * 256 + w * 64) * 8;
      gl_lds16(srcA, dA);
      gl_lds16(srcB, dB);
    }
    asm volatile("s_waitcnt vmcnt(0)" ::: "memory");
    __syncthreads();

    bf16x8 af[4][2], bfr[4][2];
#pragma unroll
    for (int mt = 0; mt < 4; mt++) {
      int row = wm * 64 + mt * 16 + r15;
#pragma unroll
      for (int kh = 0; kh < 2; kh++) {
        int off = row * 128 + ((kh * 64 + hi) ^ ((row & 7) << 4));
        af[mt][kh] = *(const bf16x8*)((const char*)lA + off);
      }
    }
#pragma unroll
    for (int nt = 0; nt < 4; nt++) {
      int row = wn * 64 + nt * 16 + r15;
#pragma unroll
      for (int kh = 0; kh < 2; kh++) {
        int off = row * 128 + ((kh * 64 + hi) ^ ((row & 7) << 4));
        bfr[nt][kh] = *(const bf16x8*)((const char*)lB + off);
      }
    }
#pragma unroll
    for (int mt = 0; mt < 4; mt++)
#pragma unroll
      for (int nt = 0; nt < 4; nt++) {
        acc[mt][nt] = MFMA(af[mt][0], bfr[nt][0], acc[mt][nt]);
        acc[mt][nt] = MFMA(af[mt][1], bfr[nt][1], acc[mt][nt]);
      }
    __syncthreads();
  }

#pragma unroll
  for (int mt = 0; mt < 4; mt++)
#pragma unroll
    for (int j = 0; j < 4; j++) {
      int row = m0 + wm * 64 + mt * 16 + g4 + j;
#pragma unroll
      for (int nt = 0; nt < 4; nt++) {
        int col = n0 + wn * 64 + nt * 16 + r15;
        float v = acc[mt][nt][j];
        if (F32OUT) ((float*)Cp)[(size_t)row * N + col] = v + bias[col];
        else        ((short*)Cp)[(size_t)row * N + col] = f2bf(v);
      }
    }
}

// ------------------------------------ in-place L2-normalize q,k (scale 1/(8n))
__global__ __launch_bounds__(256, 4) void k_norm(short* __restrict__ qkvb) {
  const int tid = threadIdx.x;
#pragma unroll 1
  for (int pass = 0; pass < 8; ++pass) {
    int uid = blockIdx.x * 256 + pass * 32 + (tid >> 3);
    int slice = uid >> 17;                  // 0: q (col 0), 1: k (col 512)
    int v = uid & 131071;                   // b|t|i|h = 1+3+10+3 bits
    int b = v >> 16, t = (v >> 13) & 7, i = (v >> 3) & 1023, h = v & 7;
    size_t addr = ((size_t)(b * NTOK + t * HW + i)) * 1536 + slice * 512 + h * 64 + (tid & 7) * 8;
    bf16x8 d = *(const bf16x8*)(qkvb + addr);
    float ss = 0.f;
#pragma unroll
    for (int e = 0; e < 8; e++) { float f = bf2f(d[e]); ss += f * f; }
    ss += __shfl_xor(ss, 1); ss += __shfl_xor(ss, 2); ss += __shfl_xor(ss, 4);
    float sc = 1.f / (8.f * fmaxf(sqrtf(ss), 1e-12f));
    bf16x8 o;
#pragma unroll
    for (int e = 0; e < 8; e++) o[e] = f2bf(bf2f(d[e]) * sc);
    *(bf16x8*)(qkvb + addr) = o;
  }
}

// ---------------------------------------------------------------- cost volume
// One WG per (bht, y), XCD-locality decode. LDS = lq(4KB) + lk(28KB) = 32KB;
// the 14KB extraction scratch ALIASES lk (barrier-protected, accs in regs).
__global__ __launch_bounds__(256, 4) void k_corr(
    const short* __restrict__ qkvb, short* __restrict__ corrI, short* __restrict__ corrU)
{
  __shared__ short lq[32 * 64];     // 4KB: q row, swizzled 128B rows
  __shared__ short lk[224 * 64];    // 28KB: k rows; first 14KB reused as scr
  short* scr = lk;                  // scratch alias (after barrier)

  const int tid = threadIdx.x;
  const int lane = tid & 63, w = tid >> 6;
  const int r15 = lane & 15, hi = (lane >> 4) * 16, g4 = (lane >> 4) * 4;
  const int pid = blockIdx.x;
  const int bht = (pid & 7) + 8 * ((pid >> 3) & 15);   // 16 bht per XCD
  const int y = pid >> 7;                              // y sweeps per XCD
  const int b = bht >> 6, head = (bht >> 3) & 7, tf = bht & 7;
  const int tk = (tf < 7) ? tf + 1 : 7;

  { // stage q: 32 rows x 128B = 256 chunks (1/thread)
    int row = tid >> 3;
    int sb = ((tid & 7) * 16) ^ ((row & 7) << 4);
    const char* src = (const char*)(qkvb + ((size_t)b * NTOK + tf * HW + y * 32 + row) * 1536 + head * 64) + sb;
    gl_lds16(src, lq + (w * 64) * 8);
  }
#pragma unroll
  for (int it = 0; it < 7; it++) { // stage k: 224 rows = 1792 chunks (7/thread)
    int chunk = it * 256 + tid;
    int row = chunk >> 3;          // p = dy*32+xx
    int dy = row >> 5, xx = row & 31;
    int ysrc = y + dy - 3;
    int sb = ((chunk & 7) * 16) ^ ((row & 7) << 4);
    if (ysrc >= 0 && ysrc < 32) {
      const char* src = (const char*)(qkvb + ((size_t)b * NTOK + tk * HW + ysrc * 32 + xx) * 1536 + 512 + head * 64) + sb;
      gl_lds16(src, lk + (it * 256 + w * 64) * 8);
    } else {
      *(bf16x8*)(lk + (size_t)chunk * 8) = (bf16x8)(short)0;
    }
  }
  asm volatile("s_waitcnt vmcnt(0)" ::: "memory");
  __syncthreads();

  // MFMA: 2 m-tiles x 14 n-tiles; wave w owns tiles t = w*7 .. w*7+6
  bf16x8 aq[2][2];
#pragma unroll
  for (int mt = 0; mt < 2; mt++) {
    int row = mt * 16 + r15;
#pragma unroll
    for (int kh = 0; kh < 2; kh++) {
      int off = row * 128 + ((kh * 64 + hi) ^ ((row & 7) << 4));
      aq[mt][kh] = *(const bf16x8*)((const char*)lq + off);
    }
  }
  f32x4 accc[7];
#pragma unroll
  for (int c = 0; c < 7; c++) {
    int t = w * 7 + c, mt = t & 1, nt = t >> 1;
    int rowB = nt * 16 + r15;
    f32x4 a = (f32x4)0.f;
#pragma unroll
    for (int kh = 0; kh < 2; kh++) {
      int off = rowB * 128 + ((kh * 64 + hi) ^ ((rowB & 7) << 4));
      bf16x8 bb = *(const bf16x8*)((const char*)lk + off);
      a = MFMA(aq[mt][kh], bb, a);
    }
    accc[c] = a;
  }
  __syncthreads();   // all lk reads done; safe to overwrite with scr

#pragma unroll
  for (int c = 0; c < 7; c++) {  // dump tiles: rows g4..g4+3 at col r15 (b64)
    int t = w * 7 + c;
    s16x4 pk;
    pk[0] = f2bf(accc[c][0]); pk[1] = f2bf(accc[c][1]);
    pk[2] = f2bf(accc[c][2]); pk[3] = f2bf(accc[c][3]);
    *(s16x4*)(scr + t * 256 + r15 * 16 + g4) = pk;
  }
  __syncthreads();

  { // gather corrI: thread -> (x, u0=8-group); contiguous 16B store
    int x = tid >> 3, u0 = (tid & 7) * 8;
    bf16x8 o;
#pragma unroll
    for (int e = 0; e < 8; e++) {
      int u = u0 + e;
      int dy = (u * 9363) >> 16;           // u/7 for u<64
      int dx = u - dy * 7;
      int xx = x + dx - 3;
      int xxc = min(max(xx, 0), 31);
      int t2 = ((min(dy, 6) * 2 + (xxc >> 4)) * 2 + (x >> 4));
      short vv = scr[t2 * 256 + (xxc & 15) * 16 + (x & 15)];
      vv = (xx == xxc && u < 49) ? vv : (short)0;
      o[e] = (u == 49) ? (short)0x3F80 : vv;   // ones row
    }
    *(bf16x8*)(corrI + ((size_t)bht * HW + y * 32 + x) * 64 + u0) = o;
  }
  { // gather corrU: thread -> (u, x0=8-group)
    int u = tid >> 2, x0 = (tid & 3) * 8;
    int dy = (u * 9363) >> 16;
    int dx = u - dy * 7;
    int dyc = min(dy, 6);
    bf16x8 o;
#pragma unroll
    for (int e = 0; e < 8; e++) {
      int x = x0 + e;
      int xx = x + dx - 3;
      int xxc = min(max(xx, 0), 31);
      int t2 = ((dyc * 2 + (xxc >> 4)) * 2 + (x >> 4));
      short vv = scr[t2 * 256 + (xxc & 15) * 16 + (x & 15)];
      vv = (xx == xxc && u < 49) ? vv : (short)0;
      o[e] = (u == 49) ? (short)0x3F80 : vv;
    }
    *(bf16x8*)(corrU + (size_t)bht * 65536 + u * HW + y * 32 + x0) = o;
  }
}

// ----------------------------------------------- v transpose: vT[bht][d][i]
__global__ __launch_bounds__(256, 2) void k_vT(const short* __restrict__ qkvb, short* __restrict__ vT)
{
  __shared__ short lt[128 * 72];  // [i][d] pad 72
  const int tid = threadIdx.x;
  const int bht = blockIdx.x >> 2;
  const int cbase = (blockIdx.x & 3) * 256;
  const int b = bht >> 6, head = (bht >> 3) & 7, tf = bht & 7;
  const size_t rowbase = ((size_t)b * NTOK + tf * HW) * 1536 + 1024 + head * 64;
  for (int c0 = cbase; c0 < cbase + 256; c0 += 128) {
    __syncthreads();
#pragma unroll
    for (int it = 0; it < 4; it++) {
      int idx = it * 256 + tid;
      int row = idx >> 3, part = idx & 7;
      bf16x8 v = *(const bf16x8*)(qkvb + rowbase + (size_t)(c0 + row) * 1536 + part * 8);
      *(bf16x8*)(lt + row * 72 + part * 8) = v;
    }
    __syncthreads();
    int d = tid & 63, blk = tid >> 6;
#pragma unroll
    for (int qq = 0; qq < 4; qq++) {
      bf16x8 o;
#pragma unroll
      for (int e = 0; e < 8; e++) o[e] = lt[(blk * 32 + qq * 8 + e) * 72 + d];
      *(bf16x8*)(vT + ((size_t)bht * 64 + d) * HW + c0 + blk * 32 + qq * 8) = o;
    }
  }
}

// --------------------------------- fused rank-50 attention, d-split x2
// grid 256: block = (bht, dh). phase1: GT[dh-half 32][u] = sum_i vT[d][i]*corrU[u][i]
// phase2: out[i][dh-half] = (corrI[i][:] . GT[d][:]) / (corrI[i][:] . c1[:])
__global__ __launch_bounds__(256, 2) void k_attn(
    const short* __restrict__ corrU, const short* __restrict__ corrI,
    const short* __restrict__ vT, short* __restrict__ out_attn)
{
  __shared__ short lV[32 * 64];
  __shared__ short lU[64 * 64];
  __shared__ short GTl[32 * 72];
  __shared__ float cl[64];
  __shared__ float cpart[256];
  const int tid = threadIdx.x, lane = tid & 63, w = tid >> 6;
  const int r15 = lane & 15, hi = (lane >> 4) * 16, g4 = (lane >> 4) * 4, g8 = (lane >> 4) * 8;
  const int bht = blockIdx.x & 127, dh = blockIdx.x >> 7;
  const int b = bht >> 6, head = (bht >> 3) & 7, tf = bht & 7;
  const int wm = w & 1, wn2 = (w >> 1) * 2;   // wave's m-tile, first n-tile

  f32x4 accP[2];
  accP[0] = (f32x4)0.f; accP[1] = (f32x4)0.f;
  float c1p = 0.f;
  const short* vbase = vT + ((size_t)bht * 64 + dh * 32) * HW;
  const short* ubase = corrU + (size_t)bht * 65536;

  for (int i0 = 0; i0 < 1024; i0 += 64) {
    { // stage lV: 32 d-rows x 128B = 256 chunks (1/thread)
      int row = tid >> 3;
      int sb = ((tid & 7) * 16) ^ ((row & 7) << 4);
      gl_lds16((const char*)(vbase + (size_t)row * HW + i0) + sb, lV + (w * 64) * 8);
    }
#pragma unroll
    for (int it = 0; it < 2; it++) { // stage lU: 64 u-rows
      int chunk = it * 256 + tid;
      int row = chunk >> 3;
      int sb = ((chunk & 7) * 16) ^ ((row & 7) << 4);
      gl_lds16((const char*)(ubase + (size_t)row * HW + i0) + sb, lU + (it * 256 + w * 64) * 8);
    }
    asm volatile("s_waitcnt vmcnt(0)" ::: "memory");
    __syncthreads();
    bf16x8 av[2];
    int rowA = wm * 16 + r15;
#pragma unroll
    for (int kh = 0; kh < 2; kh++) {
      int off = rowA * 128 + ((kh * 64 + hi) ^ ((rowA & 7) << 4));
      av[kh] = *(const bf16x8*)((const char*)lV + off);
    }
#pragma unroll
    for (int c = 0; c < 2; c++) {
      int rowB = (wn2 + c) * 16 + r15;
#pragma unroll
      for (int kh = 0; kh < 2; kh++) {
        int off = rowB * 128 + ((kh * 64 + hi) ^ ((rowB & 7) << 4));
        bf16x8 bu = *(const bf16x8*)((const char*)lU + off);
        accP[c] = MFMA(av[kh], bu, accP[c]);
      }
    }
    { // c1 partials: thread t sums lU row u=t>>2, 16 elems at part=(t&3)
      int u = tid >> 2, partc = tid & 3;
#pragma unroll
      for (int h = 0; h < 2; h++) {
        int off = u * 128 + ((partc * 32 + h * 16) ^ ((u & 7) << 4));
        bf16x8 vv = *(const bf16x8*)((const char*)lU + off);
#pragma unroll
        for (int e = 0; e < 8; e++) c1p += bf2f(vv[e]);
      }
    }
    __syncthreads();
  }
  cpart[tid] = c1p;
#pragma unroll
  for (int c = 0; c < 2; c++)
#pragma unroll
    for (int j = 0; j < 4; j++) {
      int d = wm * 16 + g4 + j, u = (wn2 + c) * 16 + r15;
      GTl[d * 72 + u] = f2bf(accP[c][j]);
    }
  __syncthreads();
  if (tid < 64) cl[tid] = cpart[4 * tid] + cpart[4 * tid + 1] + cpart[4 * tid + 2] + cpart[4 * tid + 3];
  __syncthreads();

  bf16x8 gtb[2][2];
#pragma unroll
  for (int nt = 0; nt < 2; nt++)
#pragma unroll
    for (int kh = 0; kh < 2; kh++)
      gtb[nt][kh] = *(const bf16x8*)((const char*)GTl + (nt * 16 + r15) * 144 + kh * 64 + hi);

  float c1r[2][8];
#pragma unroll
  for (int kh = 0; kh < 2; kh++)
#pragma unroll
    for (int e = 0; e < 8; e++) c1r[kh][e] = cl[kh * 32 + g8 + e];

  const short* ibase = corrI + (size_t)bht * HW * 64;
  for (int s = 0; s < 16; s++) {
    int i0 = w * 256 + s * 16;
    bf16x8 af[2];
#pragma unroll
    for (int kh = 0; kh < 2; kh++)
      af[kh] = *(const bf16x8*)(ibase + (size_t)(i0 + r15) * 64 + kh * 32 + g8);
    f32x4 a2[2];
    a2[0] = (f32x4)0.f; a2[1] = (f32x4)0.f;
#pragma unroll
    for (int nt = 0; nt < 2; nt++)
#pragma unroll
      for (int kh = 0; kh < 2; kh++) a2[nt] = MFMA(af[kh], gtb[nt][kh], a2[nt]);

    float dp = 0.f;
#pragma unroll
    for (int kh = 0; kh < 2; kh++)
#pragma unroll
      for (int e = 0; e < 8; e++) dp += bf2f(af[kh][e]) * c1r[kh][e];
    dp += __shfl_xor(dp, 16);
    dp += __shfl_xor(dp, 32);

#pragma unroll
    for (int j = 0; j < 4; j++) {
      float dj = __shfl(dp, g4 + j);
      float inv = 1.f / dj;
      int i = i0 + g4 + j;
      size_t outrow = ((size_t)b * NTOK + tf * HW + i) * 512 + head * 64 + dh * 32;
#pragma unroll
      for (int nt = 0; nt < 2; nt++)
        out_attn[outrow + nt * 16 + r15] = f2bf(a2[nt][j] * inv);
    }
  }
}

extern "C" void kernel_launch(void* const* d_in, const int* in_sizes, int n_in,
                              void* d_out, int out_size, void* d_ws, size_t ws_size,
                              hipStream_t stream) {
  (void)in_sizes; (void)n_in; (void)out_size; (void)ws_size;
  const float* x      = (const float*)d_in[0];
  const float* w_qkv  = (const float*)d_in[1];
  const float* w_proj = (const float*)d_in[2];
  const float* b_proj = (const float*)d_in[3];

  char* ws = (char*)d_ws;
  short* qkvb   = (short*)(ws);                 // 50,331,648 B [16384][1536]
  short* xb     = (short*)(ws + 50331648);      // 16,777,216 B
  short* corrU  = (short*)(ws + 67108864);      // 16,777,216 B [128][64][1024]
  short* vT     = (short*)(ws + 83886080);      // 16,777,216 B [128][64][1024]
  short* wqkvb  = (short*)(ws + 100663296);     //  1,572,864 B
  short* wprojb = (short*)(ws + 102236160);     //    524,288 B
  short* corrI    = xb;    // alias: xb dead after qkv GEMM
  short* out_attn = qkvb;  // alias: qkvb dead after corr + vT

  k_cvt<<<dim3(4096), 256, 0, stream>>>(x, xb, 1048576);
  k_cvt<<<dim3(384),  256, 0, stream>>>(w_qkv, wqkvb, 98304);
  k_cvt<<<dim3(128),  256, 0, stream>>>(w_proj, wprojb, 32768);

  k_gemm_bt<0><<<dim3(1536), 256, 0, stream>>>(xb, wqkvb, qkvb, nullptr, 16384, 1536, 512);

  k_norm<<<dim3(1024), 256, 0, stream>>>(qkvb);

  k_corr<<<dim3(4096), 256, 0, stream>>>(qkvb, corrI, corrU);
  k_vT<<<dim3(512), 256, 0, stream>>>(qkvb, vT);

  k_attn<<<dim3(256), 256, 0, stream>>>(corrU, corrI, vT, out_attn);

  k_gemm_bt<1><<<dim3(512), 256, 0, stream>>>(out_attn, wprojb, d_out, b_proj, 16384, 512, 512);
}

// Round 7
// 121.509 us; speedup vs baseline: 2.0983x; 1.8435x over previous
//
#include <hip/hip_runtime.h>
#include <hip/hip_bf16.h>
#include <stdint.h>

// CostVolumeAttention2: B=2, N=8192, C=512, heads=8, hd=64, T=8, H=W=32, U=49.
// Linearized softmax: |M|<=49/64^2=0.012 -> exp(M)=1+M to 7e-5 rel accuracy.
// attn @ v collapses to rank-50:  num = A'^T (A' v),  den = A'^T (A' 1),
// where A' = corr with a ones-row (slot u'=63), u' = dy*8+dx (pad slots zero).
// q,k are L2-normalized IN-PLACE (scale 1/(8*norm)) so corr = qn.kn directly.
// R7: k_corr v3 - 512-thread y-pair blocks, one stage+drain per 2 rows,
// split gather waves; full XCD producer->consumer chain: XCD = (b*8+tf)>>1
// matches gemm m-panel writer for norm/corr/vT/attn/proj.

#define DEVFN __device__ __forceinline__

typedef __attribute__((ext_vector_type(8))) short bf16x8;
typedef __attribute__((ext_vector_type(4))) short s16x4;
typedef __attribute__((ext_vector_type(4))) float f32x4;

DEVFN float bf2f(short s) {
  union { unsigned int u; float f; } v;
  v.u = ((unsigned int)(unsigned short)s) << 16;
  return v.f;
}
DEVFN short f2bf(float f) {
  __hip_bfloat16 h = __float2bfloat16(f);
  return *reinterpret_cast<short*>(&h);
}

DEVFN void gl_lds16(const void* g, void* l) {
  __builtin_amdgcn_global_load_lds((const __attribute__((address_space(1))) void*)g,
                                   (__attribute__((address_space(3))) void*)l, 16, 0, 0);
}

#define MFMA(a, b, c) __builtin_amdgcn_mfma_f32_16x16x32_bf16((a), (b), (c), 0, 0, 0)

#define NTOK 8192
#define HW   1024

// ------------------------------------------- fp32->bf16, 3 buffers, 1 launch
__global__ void k_cvt3(const float* __restrict__ x, const float* __restrict__ wq,
                       const float* __restrict__ wp, short* __restrict__ xb,
                       short* __restrict__ wqb, short* __restrict__ wpb) {
  int pid = blockIdx.x;
  const float* in; short* out; int i;
  if (pid < 4096)      { in = x;  out = xb;  i = pid * 256 + threadIdx.x; }
  else if (pid < 4480) { in = wq; out = wqb; i = (pid - 4096) * 256 + threadIdx.x; }
  else                 { in = wp; out = wpb; i = (pid - 4480) * 256 + threadIdx.x; }
  const float4* p = (const float4*)in + (size_t)i * 2;
  float4 a = p[0], b = p[1];
  bf16x8 r;
  r[0]=f2bf(a.x); r[1]=f2bf(a.y); r[2]=f2bf(a.z); r[3]=f2bf(a.w);
  r[4]=f2bf(b.x); r[5]=f2bf(b.y); r[6]=f2bf(b.z); r[7]=f2bf(b.w);
  *(bf16x8*)(out + (size_t)i * 8) = r;
}

// ------------------------------------------------- GEMM: C[M][N] = A * B^T
// 1D grid = 128*nblocks; XCD x owns m-panels [x*16,(x+1)*16) -> rows row>>11==x.
template<int F32OUT>
__global__ __launch_bounds__(256, 2) void k_gemm_bt(
    const short* __restrict__ A, const short* __restrict__ Bm,
    void* __restrict__ Cp, const float* __restrict__ bias, int M, int N, int K)
{
  __shared__ short lA[128 * 64];
  __shared__ short lB[128 * 64];
  const int tid = threadIdx.x;
  const int lane = tid & 63, w = tid >> 6;
  const int wm = w >> 1, wn = w & 1;
  const int r15 = lane & 15, hi = (lane >> 4) * 16, g4 = (lane >> 4) * 4;
  const int pid = blockIdx.x;
  const int m0 = ((pid & 7) * 16 + ((pid >> 3) & 15)) * 128;
  const int n0 = (pid >> 7) * 128;

  f32x4 acc[4][4];
#pragma unroll
  for (int i = 0; i < 4; i++)
#pragma unroll
    for (int j = 0; j < 4; j++) acc[i][j] = (f32x4)0.f;

  for (int k0 = 0; k0 < K; k0 += 64) {
#pragma unroll
    for (int it = 0; it < 4; it++) {
      int chunk = it * 256 + tid;
      int row = chunk >> 3;
      int sb = ((chunk & 7) * 16) ^ ((row & 7) << 4);
      const char* srcA = (const char*)(A + (size_t)(m0 + row) * K + k0) + sb;
      const char* srcB = (const char*)(Bm + (size_t)(n0 + row) * K + k0) + sb;
      gl_lds16(srcA, lA + (it * 256 + w * 64) * 8);
      gl_lds16(srcB, lB + (it * 256 + w * 64) * 8);
    }
    asm volatile("s_waitcnt vmcnt(0)" ::: "memory");
    __syncthreads();

    bf16x8 af[4][2], bfr[4][2];
#pragma unroll
    for (int mt = 0; mt < 4; mt++) {
      int row = wm * 64 + mt * 16 + r15;
#pragma unroll
      for (int kh = 0; kh < 2; kh++) {
        int off = row * 128 + ((kh * 64 + hi) ^ ((row & 7) << 4));
        af[mt][kh] = *(const bf16x8*)((const char*)lA + off);
      }
    }
#pragma unroll
    for (int nt = 0; nt < 4; nt++) {
      int row = wn * 64 + nt * 16 + r15;
#pragma unroll
      for (int kh = 0; kh < 2; kh++) {
        int off = row * 128 + ((kh * 64 + hi) ^ ((row & 7) << 4));
        bfr[nt][kh] = *(const bf16x8*)((const char*)lB + off);
      }
    }
#pragma unroll
    for (int mt = 0; mt < 4; mt++)
#pragma unroll
      for (int nt = 0; nt < 4; nt++) {
        acc[mt][nt] = MFMA(af[mt][0], bfr[nt][0], acc[mt][nt]);
        acc[mt][nt] = MFMA(af[mt][1], bfr[nt][1], acc[mt][nt]);
      }
    __syncthreads();
  }

#pragma unroll
  for (int mt = 0; mt < 4; mt++)
#pragma unroll
    for (int j = 0; j < 4; j++) {
      int row = m0 + wm * 64 + mt * 16 + g4 + j;
#pragma unroll
      for (int nt = 0; nt < 4; nt++) {
        int col = n0 + wn * 64 + nt * 16 + r15;
        float v = acc[mt][nt][j];
        if (F32OUT) ((float*)Cp)[(size_t)row * N + col] = v + bias[col];
        else        ((short*)Cp)[(size_t)row * N + col] = f2bf(v);
      }
    }
}

// ------------------------------------ in-place L2-normalize q,k (scale 1/(8n))
// XCD-pinned: block's tokens live in the local L2 (written there by the gemm).
__global__ __launch_bounds__(256, 4) void k_norm(short* __restrict__ qkvb) {
  const int tid = threadIdx.x;
  const int pid = blockIdx.x;
  const int xcd = pid & 7, idx = pid >> 3;       // idx 0..127
  const int g = 2 * xcd + (idx & 1);             // token panel b*8+t
  const int slice = (idx >> 1) & 1;              // 0:q 1:k
  const int iblk = idx >> 2;                     // 0..31
#pragma unroll 1
  for (int pass = 0; pass < 8; ++pass) {
    int unit = pass * 32 + (tid >> 3);           // 0..255
    int i = iblk * 32 + (unit >> 3);
    int h = unit & 7;
    size_t addr = ((size_t)(g * HW + i)) * 1536 + slice * 512 + h * 64 + (tid & 7) * 8;
    bf16x8 d = *(const bf16x8*)(qkvb + addr);
    float ss = 0.f;
#pragma unroll
    for (int e = 0; e < 8; e++) { float f = bf2f(d[e]); ss += f * f; }
    ss += __shfl_xor(ss, 1); ss += __shfl_xor(ss, 2); ss += __shfl_xor(ss, 4);
    float sc = 1.f / (8.f * fmaxf(sqrtf(ss), 1e-12f));
    bf16x8 o;
#pragma unroll
    for (int e = 0; e < 8; e++) o[e] = f2bf(bf2f(d[e]) * sc);
    *(bf16x8*)(qkvb + addr) = o;
  }
}

// ---------------------------------------------------------------- cost volume
// v3: 2048 blocks x 512 threads; block = (bht, y-pair). One stage (q 2 rows +
// k 8-row window, 40KB) + one vmcnt drain per block. Per y: waves 0-6 compute
// 28 Gram tiles (MFMA) + dump to scr; then waves 0-3 gather corrI, waves 4-7
// gather corrU (coalesced b128 stores). u' = dy*8+dx, ones at u'=63.
__global__ __launch_bounds__(512, 4) void k_corr(
    const short* __restrict__ qkvb, short* __restrict__ corrI, short* __restrict__ corrU)
{
  __shared__ short stg[2560 * 8];   // 40KB: rows 0-63 q (y0,y0+1), 64-319 k slots 0-7
  __shared__ short scr[28 * 256];   // 14KB: tile t -> [p&15][x&15]

  const int tid = threadIdx.x;
  const int lane = tid & 63, w = tid >> 6;
  const int r15 = lane & 15, hi = (lane >> 4) * 16, g4 = (lane >> 4) * 4;
  const int pid = blockIdx.x;
  const int xcd = pid & 7, idx = pid >> 3;       // idx 0..255
  const int g = 2 * xcd + (idx & 1);
  const int head = (idx >> 1) & 7;
  const int y0 = (idx >> 4) * 2;                 // 0,2,..,30
  const int b = g >> 3, tf = g & 7;
  const int bht = b * 64 + head * 8 + tf;
  const int tk = (tf < 7) ? tf + 1 : 7;
  const size_t qbase = ((size_t)(g * HW)) * 1536 + head * 64;
  const size_t kbase = ((size_t)((b * 8 + tk) * HW)) * 1536 + 512 + head * 64;

  // ---- stage: 2560 16B-chunks, 5 per thread, one drain
#pragma unroll
  for (int i = 0; i < 5; i++) {
    int c = i * 512 + tid;
    int row = c >> 3;
    int sb = ((c & 7) * 16) ^ ((row & 7) << 4);
    short* dst = stg + (i * 512 + w * 64) * 8;   // wave-uniform base
    if (i == 0) {  // q: rows y0, y0+1
      int j = c >> 8, px = (c >> 3) & 31;
      gl_lds16((const char*)(qkvb + qbase + (size_t)((y0 + j) * 32 + px) * 1536) + sb, dst);
    } else {       // k: slots 0..7 -> rows y0-3 .. y0+4
      int c2 = c - 512;
      int slot = c2 >> 8, px = (c2 >> 3) & 31;
      int r = y0 - 3 + slot;
      if (r >= 0 && r < 32)
        gl_lds16((const char*)(qkvb + kbase + (size_t)(r * 32 + px) * 1536) + sb, dst);
      else
        *(bf16x8*)(stg + (size_t)c * 8) = (bf16x8)(short)0;
    }
  }
  asm volatile("s_waitcnt vmcnt(0)" ::: "memory");
  __syncthreads();

#pragma unroll 1
  for (int j = 0; j < 2; j++) {
    const int y = y0 + j;
    if (w < 7) {
      // A-frags: q row y, 2 m-tiles
      bf16x8 aq[2][2];
#pragma unroll
      for (int mt = 0; mt < 2; mt++) {
        int row = j * 32 + mt * 16 + r15;
#pragma unroll
        for (int kh = 0; kh < 2; kh++) {
          int off = row * 128 + ((kh * 64 + hi) ^ ((row & 7) << 4));
          aq[mt][kh] = *(const bf16x8*)((const char*)stg + off);
        }
      }
      // 4 tiles per wave: t = w*4+c in 0..27; nt = t>>1 (dy = nt>>1, xh = nt&1)
#pragma unroll
      for (int c = 0; c < 4; c++) {
        int t = w * 4 + c, nt = t >> 1, mt = t & 1;
        int dy = nt >> 1, xh = nt & 1;
        int slot = dy + j;
        int xx = xh * 16 + r15;
        int rowB = 64 + slot * 32 + xx;
        f32x4 a = (f32x4)0.f;
#pragma unroll
        for (int kh = 0; kh < 2; kh++) {
          int off = rowB * 128 + ((kh * 64 + hi) ^ ((rowB & 7) << 4));
          bf16x8 bb = *(const bf16x8*)((const char*)stg + off);
          a = MFMA(aq[mt][kh], bb, a);
        }
        s16x4 pk;
        pk[0] = f2bf(a[0]); pk[1] = f2bf(a[1]); pk[2] = f2bf(a[2]); pk[3] = f2bf(a[3]);
        *(s16x4*)(scr + t * 256 + r15 * 16 + g4) = pk;   // [p=r15][x=g4..g4+3]
      }
    }
    __syncthreads();

    if (tid < 256) {  // gather corrI: (x, u-octet)
      int x = tid >> 3, u0 = (tid & 7) * 8;
      bf16x8 o;
#pragma unroll
      for (int e = 0; e < 8; e++) {
        int u = u0 + e;
        int dy = u >> 3, dx = u & 7;
        int xx = x + dx - 3;
        int dyc = (dy > 6) ? 6 : dy;
        int t2 = (dyc * 2 + ((xx & 31) >> 4)) * 2 + (x >> 4);
        short vv = scr[t2 * 256 + (xx & 15) * 16 + (x & 15)];
        bool ok = (dx < 7) && (dy < 7) && (xx >= 0) && (xx < 32);
        short res = ok ? vv : (short)0;
        o[e] = (u == 63) ? (short)0x3F80 : res;
      }
      *(bf16x8*)(corrI + ((size_t)bht * HW + y * 32 + x) * 64 + u0) = o;
    } else {          // gather corrU: (u, x-octet)
      int tt = tid - 256;
      int u = tt >> 2, x0 = (tt & 3) * 8;
      int dy = u >> 3, dx = u & 7;
      int dyc = (dy > 6) ? 6 : dy;
      bf16x8 o;
#pragma unroll
      for (int e = 0; e < 8; e++) {
        int x = x0 + e;
        int xx = x + dx - 3;
        int t2 = (dyc * 2 + ((xx & 31) >> 4)) * 2 + (x >> 4);
        short vv = scr[t2 * 256 + (xx & 15) * 16 + (x & 15)];
        bool ok = (dx < 7) && (dy < 7) && (xx >= 0) && (xx < 32);
        short res = ok ? vv : (short)0;
        o[e] = (u == 63) ? (short)0x3F80 : res;
      }
      *(bf16x8*)(corrU + (size_t)bht * 65536 + u * HW + y * 32 + x0) = o;
    }
    __syncthreads();   // scr reused next y
  }
}

// ----------------------------------------------- v transpose: vT[bht][d][i]
__global__ __launch_bounds__(256, 2) void k_vT(const short* __restrict__ qkvb, short* __restrict__ vT)
{
  __shared__ short lt[128 * 72];  // [i][d] pad 72
  const int tid = threadIdx.x;
  const int pid = blockIdx.x;
  const int xcd = pid & 7, idx = pid >> 3;   // 0..63
  const int g = 2 * xcd + (idx & 1);
  const int head = (idx >> 1) & 7;
  const int cbase = (idx >> 4) * 256;
  const int b = g >> 3, tf = g & 7;
  const int bht = b * 64 + head * 8 + tf;
  const size_t rowbase = ((size_t)(g * HW)) * 1536 + 1024 + head * 64;
  for (int c0 = cbase; c0 < cbase + 256; c0 += 128) {
    __syncthreads();
#pragma unroll
    for (int it = 0; it < 4; it++) {
      int idx2 = it * 256 + tid;
      int row = idx2 >> 3, part = idx2 & 7;
      bf16x8 v = *(const bf16x8*)(qkvb + rowbase + (size_t)(c0 + row) * 1536 + part * 8);
      *(bf16x8*)(lt + row * 72 + part * 8) = v;
    }
    __syncthreads();
    int d = tid & 63, blk = tid >> 6;
#pragma unroll
    for (int qq = 0; qq < 4; qq++) {
      bf16x8 o;
#pragma unroll
      for (int e = 0; e < 8; e++) o[e] = lt[(blk * 32 + qq * 8 + e) * 72 + d];
      *(bf16x8*)(vT + ((size_t)bht * 64 + d) * HW + c0 + blk * 32 + qq * 8) = o;
    }
  }
}

// --------------------------------- fused rank-50 attention, d-split x2
__global__ __launch_bounds__(256, 2) void k_attn(
    const short* __restrict__ corrU, const short* __restrict__ corrI,
    const short* __restrict__ vT, short* __restrict__ out_attn)
{
  __shared__ short lV[32 * 64];
  __shared__ short lU[64 * 64];
  __shared__ short GTl[32 * 72];
  __shared__ float cl[64];
  __shared__ float cpart[256];
  const int tid = threadIdx.x, lane = tid & 63, w = tid >> 6;
  const int r15 = lane & 15, hi = (lane >> 4) * 16, g4 = (lane >> 4) * 4, g8 = (lane >> 4) * 8;
  const int pid = blockIdx.x;
  const int xcd = pid & 7, idx = pid >> 3;   // 0..31
  const int g = 2 * xcd + (idx & 1);
  const int head = (idx >> 1) & 7;
  const int dh = (idx >> 4) & 1;
  const int b = g >> 3, tf = g & 7;
  const int bht = b * 64 + head * 8 + tf;
  const int wm = w & 1, wn2 = (w >> 1) * 2;

  f32x4 accP[2];
  accP[0] = (f32x4)0.f; accP[1] = (f32x4)0.f;
  float c1p = 0.f;
  const short* vbase = vT + ((size_t)bht * 64 + dh * 32) * HW;
  const short* ubase = corrU + (size_t)bht * 65536;

  for (int i0 = 0; i0 < 1024; i0 += 64) {
    { int row = tid >> 3;
      int sb = ((tid & 7) * 16) ^ ((row & 7) << 4);
      gl_lds16((const char*)(vbase + (size_t)row * HW + i0) + sb, lV + (w * 64) * 8);
    }
#pragma unroll
    for (int it = 0; it < 2; it++) {
      int chunk = it * 256 + tid;
      int row = chunk >> 3;
      int sb = ((chunk & 7) * 16) ^ ((row & 7) << 4);
      gl_lds16((const char*)(ubase + (size_t)row * HW + i0) + sb, lU + (it * 256 + w * 64) * 8);
    }
    asm volatile("s_waitcnt vmcnt(0)" ::: "memory");
    __syncthreads();
    bf16x8 av[2];
    int rowA = wm * 16 + r15;
#pragma unroll
    for (int kh = 0; kh < 2; kh++) {
      int off = rowA * 128 + ((kh * 64 + hi) ^ ((rowA & 7) << 4));
      av[kh] = *(const bf16x8*)((const char*)lV + off);
    }
#pragma unroll
    for (int c = 0; c < 2; c++) {
      int rowB = (wn2 + c) * 16 + r15;
#pragma unroll
      for (int kh = 0; kh < 2; kh++) {
        int off = rowB * 128 + ((kh * 64 + hi) ^ ((rowB & 7) << 4));
        bf16x8 bu = *(const bf16x8*)((const char*)lU + off);
        accP[c] = MFMA(av[kh], bu, accP[c]);
      }
    }
    { int u = tid >> 2, partc = tid & 3;
#pragma unroll
      for (int h = 0; h < 2; h++) {
        int off = u * 128 + ((partc * 32 + h * 16) ^ ((u & 7) << 4));
        bf16x8 vv = *(const bf16x8*)((const char*)lU + off);
#pragma unroll
        for (int e = 0; e < 8; e++) c1p += bf2f(vv[e]);
      }
    }
    __syncthreads();
  }
  cpart[tid] = c1p;
#pragma unroll
  for (int c = 0; c < 2; c++)
#pragma unroll
    for (int j = 0; j < 4; j++) {
      int d = wm * 16 + g4 + j, u = (wn2 + c) * 16 + r15;
      GTl[d * 72 + u] = f2bf(accP[c][j]);
    }
  __syncthreads();
  if (tid < 64) cl[tid] = cpart[4 * tid] + cpart[4 * tid + 1] + cpart[4 * tid + 2] + cpart[4 * tid + 3];
  __syncthreads();

  bf16x8 gtb[2][2];
#pragma unroll
  for (int nt = 0; nt < 2; nt++)
#pragma unroll
    for (int kh = 0; kh < 2; kh++)
      gtb[nt][kh] = *(const bf16x8*)((const char*)GTl + (nt * 16 + r15) * 144 + kh * 64 + hi);

  float c1r[2][8];
#pragma unroll
  for (int kh = 0; kh < 2; kh++)
#pragma unroll
    for (int e = 0; e < 8; e++) c1r[kh][e] = cl[kh * 32 + g8 + e];

  const short* ibase = corrI + (size_t)bht * HW * 64;
  for (int s = 0; s < 16; s++) {
    int i0 = w * 256 + s * 16;
    bf16x8 af[2];
#pragma unroll
    for (int kh = 0; kh < 2; kh++)
      af[kh] = *(const bf16x8*)(ibase + (size_t)(i0 + r15) * 64 + kh * 32 + g8);
    f32x4 a2[2];
    a2[0] = (f32x4)0.f; a2[1] = (f32x4)0.f;
#pragma unroll
    for (int nt = 0; nt < 2; nt++)
#pragma unroll
      for (int kh = 0; kh < 2; kh++) a2[nt] = MFMA(af[kh], gtb[nt][kh], a2[nt]);

    float dp = 0.f;
#pragma unroll
    for (int kh = 0; kh < 2; kh++)
#pragma unroll
      for (int e = 0; e < 8; e++) dp += bf2f(af[kh][e]) * c1r[kh][e];
    dp += __shfl_xor(dp, 16);
    dp += __shfl_xor(dp, 32);

#pragma unroll
    for (int j = 0; j < 4; j++) {
      float dj = __shfl(dp, g4 + j);
      float inv = 1.f / dj;
      int i = i0 + g4 + j;
      size_t outrow = ((size_t)(g * HW + i)) * 512 + head * 64 + dh * 32;
#pragma unroll
      for (int nt = 0; nt < 2; nt++)
        out_attn[outrow + nt * 16 + r15] = f2bf(a2[nt][j] * inv);
    }
  }
}

extern "C" void kernel_launch(void* const* d_in, const int* in_sizes, int n_in,
                              void* d_out, int out_size, void* d_ws, size_t ws_size,
                              hipStream_t stream) {
  (void)in_sizes; (void)n_in; (void)out_size; (void)ws_size;
  const float* x      = (const float*)d_in[0];
  const float* w_qkv  = (const float*)d_in[1];
  const float* w_proj = (const float*)d_in[2];
  const float* b_proj = (const float*)d_in[3];

  char* ws = (char*)d_ws;
  short* qkvb   = (short*)(ws);                 // 50,331,648 B [16384][1536]
  short* xb     = (short*)(ws + 50331648);      // 16,777,216 B
  short* corrU  = (short*)(ws + 67108864);      // 16,777,216 B [128][64][1024]
  short* vT     = (short*)(ws + 83886080);      // 16,777,216 B [128][64][1024]
  short* wqkvb  = (short*)(ws + 100663296);     //  1,572,864 B
  short* wprojb = (short*)(ws + 102236160);     //    524,288 B
  short* corrI    = xb;    // alias: xb dead after qkv GEMM
  short* out_attn = qkvb;  // alias: qkvb dead after corr + vT

  k_cvt3<<<dim3(4608), 256, 0, stream>>>(x, w_qkv, w_proj, xb, wqkvb, wprojb);

  k_gemm_bt<0><<<dim3(1536), 256, 0, stream>>>(xb, wqkvb, qkvb, nullptr, 16384, 1536, 512);

  k_norm<<<dim3(1024), 256, 0, stream>>>(qkvb);

  k_corr<<<dim3(2048), 512, 0, stream>>>(qkvb, corrI, corrU);
  k_vT<<<dim3(512), 256, 0, stream>>>(qkvb, vT);

  k_attn<<<dim3(256), 256, 0, stream>>>(corrU, corrI, vT, out_attn);

  k_gemm_bt<1><<<dim3(512), 256, 0, stream>>>(out_attn, wprojb, d_out, b_proj, 16384, 512, 512);
}

// Round 8
// 111.544 us; speedup vs baseline: 2.2857x; 1.0893x over previous
//
#include <hip/hip_runtime.h>
#include <hip/hip_bf16.h>
#include <stdint.h>

// CostVolumeAttention2: B=2, N=8192, C=512, heads=8, hd=64, T=8, H=W=32, U=49.
// Linearized softmax: |M|<=49/64^2=0.012 -> exp(M)=1+M to 7e-5 rel accuracy.
// attn @ v collapses to rank-50:  num = A'^T (A' v),  den = A'^T (A' 1),
// where A' = corr with a ones-row (slot u'=63), u' = dy*8+dx (pad slots zero).
// R8: q/k L2-norm fused into the qkv GEMM epilogue (each wave owns exactly one
// head's 64 cols in fp32 accs); vT production fused into k_corr (block owns
// exactly the 64 v-rows of its y-pair). 5 kernels total.

#define DEVFN __device__ __forceinline__

typedef __attribute__((ext_vector_type(8))) short bf16x8;
typedef __attribute__((ext_vector_type(4))) short s16x4;
typedef __attribute__((ext_vector_type(4))) float f32x4;

DEVFN float bf2f(short s) {
  union { unsigned int u; float f; } v;
  v.u = ((unsigned int)(unsigned short)s) << 16;
  return v.f;
}
DEVFN short f2bf(float f) {
  __hip_bfloat16 h = __float2bfloat16(f);
  return *reinterpret_cast<short*>(&h);
}

DEVFN void gl_lds16(const void* g, void* l) {
  __builtin_amdgcn_global_load_lds((const __attribute__((address_space(1))) void*)g,
                                   (__attribute__((address_space(3))) void*)l, 16, 0, 0);
}

#define MFMA(a, b, c) __builtin_amdgcn_mfma_f32_16x16x32_bf16((a), (b), (c), 0, 0, 0)

#define NTOK 8192
#define HW   1024

// ------------------------------------------- fp32->bf16, 3 buffers, 1 launch
__global__ void k_cvt3(const float* __restrict__ x, const float* __restrict__ wq,
                       const float* __restrict__ wp, short* __restrict__ xb,
                       short* __restrict__ wqb, short* __restrict__ wpb) {
  int pid = blockIdx.x;
  const float* in; short* out; int i;
  if (pid < 4096)      { in = x;  out = xb;  i = pid * 256 + threadIdx.x; }
  else if (pid < 4480) { in = wq; out = wqb; i = (pid - 4096) * 256 + threadIdx.x; }
  else                 { in = wp; out = wpb; i = (pid - 4480) * 256 + threadIdx.x; }
  const float4* p = (const float4*)in + (size_t)i * 2;
  float4 a = p[0], b = p[1];
  bf16x8 r;
  r[0]=f2bf(a.x); r[1]=f2bf(a.y); r[2]=f2bf(a.z); r[3]=f2bf(a.w);
  r[4]=f2bf(b.x); r[5]=f2bf(b.y); r[6]=f2bf(b.z); r[7]=f2bf(b.w);
  *(bf16x8*)(out + (size_t)i * 8) = r;
}

// ------------------------------------------------- GEMM: C[M][N] = A * B^T
// 1D grid = 128*nblocks; XCD x owns m-panels [x*16,(x+1)*16).
// F32OUT==0 (qkv): cols < 1024 (q,k slices) are L2-normalized per 64-col head
// vector in the epilogue (wave owns exactly cols [n0+wn*64, +64)).
template<int F32OUT>
__global__ __launch_bounds__(256, 2) void k_gemm_bt(
    const short* __restrict__ A, const short* __restrict__ Bm,
    void* __restrict__ Cp, const float* __restrict__ bias, int M, int N, int K)
{
  __shared__ short lA[128 * 64];
  __shared__ short lB[128 * 64];
  const int tid = threadIdx.x;
  const int lane = tid & 63, w = tid >> 6;
  const int wm = w >> 1, wn = w & 1;
  const int r15 = lane & 15, hi = (lane >> 4) * 16, g4 = (lane >> 4) * 4;
  const int pid = blockIdx.x;
  const int m0 = ((pid & 7) * 16 + ((pid >> 3) & 15)) * 128;
  const int n0 = (pid >> 7) * 128;

  f32x4 acc[4][4];
#pragma unroll
  for (int i = 0; i < 4; i++)
#pragma unroll
    for (int j = 0; j < 4; j++) acc[i][j] = (f32x4)0.f;

  for (int k0 = 0; k0 < K; k0 += 64) {
#pragma unroll
    for (int it = 0; it < 4; it++) {
      int chunk = it * 256 + tid;
      int row = chunk >> 3;
      int sb = ((chunk & 7) * 16) ^ ((row & 7) << 4);
      const char* srcA = (const char*)(A + (size_t)(m0 + row) * K + k0) + sb;
      const char* srcB = (const char*)(Bm + (size_t)(n0 + row) * K + k0) + sb;
      gl_lds16(srcA, lA + (it * 256 + w * 64) * 8);
      gl_lds16(srcB, lB + (it * 256 + w * 64) * 8);
    }
    asm volatile("s_waitcnt vmcnt(0)" ::: "memory");
    __syncthreads();

    bf16x8 af[4][2], bfr[4][2];
#pragma unroll
    for (int mt = 0; mt < 4; mt++) {
      int row = wm * 64 + mt * 16 + r15;
#pragma unroll
      for (int kh = 0; kh < 2; kh++) {
        int off = row * 128 + ((kh * 64 + hi) ^ ((row & 7) << 4));
        af[mt][kh] = *(const bf16x8*)((const char*)lA + off);
      }
    }
#pragma unroll
    for (int nt = 0; nt < 4; nt++) {
      int row = wn * 64 + nt * 16 + r15;
#pragma unroll
      for (int kh = 0; kh < 2; kh++) {
        int off = row * 128 + ((kh * 64 + hi) ^ ((row & 7) << 4));
        bfr[nt][kh] = *(const bf16x8*)((const char*)lB + off);
      }
    }
#pragma unroll
    for (int mt = 0; mt < 4; mt++)
#pragma unroll
      for (int nt = 0; nt < 4; nt++) {
        acc[mt][nt] = MFMA(af[mt][0], bfr[nt][0], acc[mt][nt]);
        acc[mt][nt] = MFMA(af[mt][1], bfr[nt][1], acc[mt][nt]);
      }
    __syncthreads();
  }

  if (F32OUT == 0 && n0 < 1024) {
    // normalize each row's 64-col head vector: wave holds it in acc[mt][*][j]
#pragma unroll
    for (int mt = 0; mt < 4; mt++)
#pragma unroll
      for (int j = 0; j < 4; j++) {
        float ss = 0.f;
#pragma unroll
        for (int nt = 0; nt < 4; nt++) ss += acc[mt][nt][j] * acc[mt][nt][j];
        ss += __shfl_xor(ss, 1); ss += __shfl_xor(ss, 2);
        ss += __shfl_xor(ss, 4); ss += __shfl_xor(ss, 8);
        float sc = 1.f / (8.f * fmaxf(sqrtf(ss), 1e-12f));
#pragma unroll
        for (int nt = 0; nt < 4; nt++) acc[mt][nt][j] *= sc;
      }
  }

#pragma unroll
  for (int mt = 0; mt < 4; mt++)
#pragma unroll
    for (int j = 0; j < 4; j++) {
      int row = m0 + wm * 64 + mt * 16 + g4 + j;
#pragma unroll
      for (int nt = 0; nt < 4; nt++) {
        int col = n0 + wn * 64 + nt * 16 + r15;
        float v = acc[mt][nt][j];
        if (F32OUT) ((float*)Cp)[(size_t)row * N + col] = v + bias[col];
        else        ((short*)Cp)[(size_t)row * N + col] = f2bf(v);
      }
    }
}

// ---------------------------------------------------------------- cost volume
// v3+vT: 2048 blocks x 512 threads; block = (bht, y-pair). One stage (q 2 rows
// + k 8-row window, 40KB) + one drain. Per y: waves 0-6 MFMA 28 Gram tiles ->
// scr; waves split gather corrI/corrU (coalesced b128). Epilogue: stage the
// block's 64 v-rows (8KB) into scr, transpose, write vT. u'=dy*8+dx, ones @63.
__global__ __launch_bounds__(512, 4) void k_corr(
    const short* __restrict__ qkvb, short* __restrict__ corrI,
    short* __restrict__ corrU, short* __restrict__ vT)
{
  __shared__ short stg[2560 * 8];   // 40KB: rows 0-63 q (y0,y0+1), 64-319 k slots
  __shared__ short scr[28 * 256];   // 14KB: corr tiles; reused for v transpose

  const int tid = threadIdx.x;
  const int lane = tid & 63, w = tid >> 6;
  const int r15 = lane & 15, hi = (lane >> 4) * 16, g4 = (lane >> 4) * 4;
  const int pid = blockIdx.x;
  const int xcd = pid & 7, idx = pid >> 3;       // idx 0..255
  const int g = 2 * xcd + (idx & 1);
  const int head = (idx >> 1) & 7;
  const int y0 = (idx >> 4) * 2;                 // 0,2,..,30
  const int b = g >> 3, tf = g & 7;
  const int bht = b * 64 + head * 8 + tf;
  const int tk = (tf < 7) ? tf + 1 : 7;
  const size_t qbase = ((size_t)(g * HW)) * 1536 + head * 64;
  const size_t kbase = ((size_t)((b * 8 + tk) * HW)) * 1536 + 512 + head * 64;

  // ---- stage: 2560 16B-chunks, 5 per thread, one drain
#pragma unroll
  for (int i = 0; i < 5; i++) {
    int c = i * 512 + tid;
    int row = c >> 3;
    int sb = ((c & 7) * 16) ^ ((row & 7) << 4);
    short* dst = stg + (i * 512 + w * 64) * 8;   // wave-uniform base
    if (i == 0) {  // q: rows y0, y0+1
      int j = c >> 8, px = (c >> 3) & 31;
      gl_lds16((const char*)(qkvb + qbase + (size_t)((y0 + j) * 32 + px) * 1536) + sb, dst);
    } else {       // k: slots 0..7 -> rows y0-3 .. y0+4
      int c2 = c - 512;
      int slot = c2 >> 8, px = (c2 >> 3) & 31;
      int r = y0 - 3 + slot;
      if (r >= 0 && r < 32)
        gl_lds16((const char*)(qkvb + kbase + (size_t)(r * 32 + px) * 1536) + sb, dst);
      else
        *(bf16x8*)(stg + (size_t)c * 8) = (bf16x8)(short)0;
    }
  }
  asm volatile("s_waitcnt vmcnt(0)" ::: "memory");
  __syncthreads();

#pragma unroll 1
  for (int j = 0; j < 2; j++) {
    const int y = y0 + j;
    if (w < 7) {
      bf16x8 aq[2][2];
#pragma unroll
      for (int mt = 0; mt < 2; mt++) {
        int row = j * 32 + mt * 16 + r15;
#pragma unroll
        for (int kh = 0; kh < 2; kh++) {
          int off = row * 128 + ((kh * 64 + hi) ^ ((row & 7) << 4));
          aq[mt][kh] = *(const bf16x8*)((const char*)stg + off);
        }
      }
#pragma unroll
      for (int c = 0; c < 4; c++) {
        int t = w * 4 + c, nt = t >> 1, mt = t & 1;
        int dy = nt >> 1, xh = nt & 1;
        int slot = dy + j;
        int xx = xh * 16 + r15;
        int rowB = 64 + slot * 32 + xx;
        f32x4 a = (f32x4)0.f;
#pragma unroll
        for (int kh = 0; kh < 2; kh++) {
          int off = rowB * 128 + ((kh * 64 + hi) ^ ((rowB & 7) << 4));
          bf16x8 bb = *(const bf16x8*)((const char*)stg + off);
          a = MFMA(aq[mt][kh], bb, a);
        }
        s16x4 pk;
        pk[0] = f2bf(a[0]); pk[1] = f2bf(a[1]); pk[2] = f2bf(a[2]); pk[3] = f2bf(a[3]);
        *(s16x4*)(scr + t * 256 + r15 * 16 + g4) = pk;   // [p=r15][x=g4..g4+3]
      }
    }
    __syncthreads();

    if (tid < 256) {  // gather corrI: (x, u-octet)
      int x = tid >> 3, u0 = (tid & 7) * 8;
      bf16x8 o;
#pragma unroll
      for (int e = 0; e < 8; e++) {
        int u = u0 + e;
        int dy = u >> 3, dx = u & 7;
        int xx = x + dx - 3;
        int dyc = (dy > 6) ? 6 : dy;
        int t2 = (dyc * 2 + ((xx & 31) >> 4)) * 2 + (x >> 4);
        short vv = scr[t2 * 256 + (xx & 15) * 16 + (x & 15)];
        bool ok = (dx < 7) && (dy < 7) && (xx >= 0) && (xx < 32);
        short res = ok ? vv : (short)0;
        o[e] = (u == 63) ? (short)0x3F80 : res;
      }
      *(bf16x8*)(corrI + ((size_t)bht * HW + y * 32 + x) * 64 + u0) = o;
    } else {          // gather corrU: (u, x-octet)
      int tt = tid - 256;
      int u = tt >> 2, x0 = (tt & 3) * 8;
      int dy = u >> 3, dx = u & 7;
      int dyc = (dy > 6) ? 6 : dy;
      bf16x8 o;
#pragma unroll
      for (int e = 0; e < 8; e++) {
        int x = x0 + e;
        int xx = x + dx - 3;
        int t2 = (dyc * 2 + ((xx & 31) >> 4)) * 2 + (x >> 4);
        short vv = scr[t2 * 256 + (xx & 15) * 16 + (x & 15)];
        bool ok = (dx < 7) && (dy < 7) && (xx >= 0) && (xx < 32);
        short res = ok ? vv : (short)0;
        o[e] = (u == 63) ? (short)0x3F80 : res;
      }
      *(bf16x8*)(corrU + (size_t)bht * 65536 + u * HW + y * 32 + x0) = o;
    }
    __syncthreads();   // scr reused (next y / v transpose)
  }

  // ---- vT: stage the block's 64 v rows (linear [i][64], 8KB) and transpose
  {
    int c = tid;                                 // 512 chunks, 1/thread
    int i = c >> 3;
    gl_lds16((const char*)(qkvb + ((size_t)(g * HW + y0 * 32 + i)) * 1536 + 1024 + head * 64)
                 + (c & 7) * 16,
             scr + (w * 64) * 8);                // wave-uniform base, linear
  }
  asm volatile("s_waitcnt vmcnt(0)" ::: "memory");
  __syncthreads();
  {
    int d = tid >> 3, i0w = (tid & 7) * 8;
    bf16x8 o;
#pragma unroll
    for (int e = 0; e < 8; e++) o[e] = scr[(i0w + e) * 64 + d];
    *(bf16x8*)(vT + ((size_t)bht * 64 + d) * HW + y0 * 32 + i0w) = o;
  }
}

// --------------------------------- fused rank-50 attention, d-split x2
__global__ __launch_bounds__(256, 2) void k_attn(
    const short* __restrict__ corrU, const short* __restrict__ corrI,
    const short* __restrict__ vT, short* __restrict__ out_attn)
{
  __shared__ short lV[32 * 64];
  __shared__ short lU[64 * 64];
  __shared__ short GTl[32 * 72];
  __shared__ float cl[64];
  __shared__ float cpart[256];
  const int tid = threadIdx.x, lane = tid & 63, w = tid >> 6;
  const int r15 = lane & 15, hi = (lane >> 4) * 16, g4 = (lane >> 4) * 4, g8 = (lane >> 4) * 8;
  const int pid = blockIdx.x;
  const int xcd = pid & 7, idx = pid >> 3;   // 0..31
  const int g = 2 * xcd + (idx & 1);
  const int head = (idx >> 1) & 7;
  const int dh = (idx >> 4) & 1;
  const int b = g >> 3, tf = g & 7;
  const int bht = b * 64 + head * 8 + tf;
  const int wm = w & 1, wn2 = (w >> 1) * 2;

  f32x4 accP[2];
  accP[0] = (f32x4)0.f; accP[1] = (f32x4)0.f;
  float c1p = 0.f;
  const short* vbase = vT + ((size_t)bht * 64 + dh * 32) * HW;
  const short* ubase = corrU + (size_t)bht * 65536;

  for (int i0 = 0; i0 < 1024; i0 += 64) {
    { int row = tid >> 3;
      int sb = ((tid & 7) * 16) ^ ((row & 7) << 4);
      gl_lds16((const char*)(vbase + (size_t)row * HW + i0) + sb, lV + (w * 64) * 8);
    }
#pragma unroll
    for (int it = 0; it < 2; it++) {
      int chunk = it * 256 + tid;
      int row = chunk >> 3;
      int sb = ((chunk & 7) * 16) ^ ((row & 7) << 4);
      gl_lds16((const char*)(ubase + (size_t)row * HW + i0) + sb, lU + (it * 256 + w * 64) * 8);
    }
    asm volatile("s_waitcnt vmcnt(0)" ::: "memory");
    __syncthreads();
    bf16x8 av[2];
    int rowA = wm * 16 + r15;
#pragma unroll
    for (int kh = 0; kh < 2; kh++) {
      int off = rowA * 128 + ((kh * 64 + hi) ^ ((rowA & 7) << 4));
      av[kh] = *(const bf16x8*)((const char*)lV + off);
    }
#pragma unroll
    for (int c = 0; c < 2; c++) {
      int rowB = (wn2 + c) * 16 + r15;
#pragma unroll
      for (int kh = 0; kh < 2; kh++) {
        int off = rowB * 128 + ((kh * 64 + hi) ^ ((rowB & 7) << 4));
        bf16x8 bu = *(const bf16x8*)((const char*)lU + off);
        accP[c] = MFMA(av[kh], bu, accP[c]);
      }
    }
    { int u = tid >> 2, partc = tid & 3;
#pragma unroll
      for (int h = 0; h < 2; h++) {
        int off = u * 128 + ((partc * 32 + h * 16) ^ ((u & 7) << 4));
        bf16x8 vv = *(const bf16x8*)((const char*)lU + off);
#pragma unroll
        for (int e = 0; e < 8; e++) c1p += bf2f(vv[e]);
      }
    }
    __syncthreads();
  }
  cpart[tid] = c1p;
#pragma unroll
  for (int c = 0; c < 2; c++)
#pragma unroll
    for (int j = 0; j < 4; j++) {
      int d = wm * 16 + g4 + j, u = (wn2 + c) * 16 + r15;
      GTl[d * 72 + u] = f2bf(accP[c][j]);
    }
  __syncthreads();
  if (tid < 64) cl[tid] = cpart[4 * tid] + cpart[4 * tid + 1] + cpart[4 * tid + 2] + cpart[4 * tid + 3];
  __syncthreads();

  bf16x8 gtb[2][2];
#pragma unroll
  for (int nt = 0; nt < 2; nt++)
#pragma unroll
    for (int kh = 0; kh < 2; kh++)
      gtb[nt][kh] = *(const bf16x8*)((const char*)GTl + (nt * 16 + r15) * 144 + kh * 64 + hi);

  float c1r[2][8];
#pragma unroll
  for (int kh = 0; kh < 2; kh++)
#pragma unroll
    for (int e = 0; e < 8; e++) c1r[kh][e] = cl[kh * 32 + g8 + e];

  const short* ibase = corrI + (size_t)bht * HW * 64;
  for (int s = 0; s < 16; s++) {
    int i0 = w * 256 + s * 16;
    bf16x8 af[2];
#pragma unroll
    for (int kh = 0; kh < 2; kh++)
      af[kh] = *(const bf16x8*)(ibase + (size_t)(i0 + r15) * 64 + kh * 32 + g8);
    f32x4 a2[2];
    a2[0] = (f32x4)0.f; a2[1] = (f32x4)0.f;
#pragma unroll
    for (int nt = 0; nt < 2; nt++)
#pragma unroll
      for (int kh = 0; kh < 2; kh++) a2[nt] = MFMA(af[kh], gtb[nt][kh], a2[nt]);

    float dp = 0.f;
#pragma unroll
    for (int kh = 0; kh < 2; kh++)
#pragma unroll
      for (int e = 0; e < 8; e++) dp += bf2f(af[kh][e]) * c1r[kh][e];
    dp += __shfl_xor(dp, 16);
    dp += __shfl_xor(dp, 32);

#pragma unroll
    for (int j = 0; j < 4; j++) {
      float dj = __shfl(dp, g4 + j);
      float inv = 1.f / dj;
      int i = i0 + g4 + j;
      size_t outrow = ((size_t)(g * HW + i)) * 512 + head * 64 + dh * 32;
#pragma unroll
      for (int nt = 0; nt < 2; nt++)
        out_attn[outrow + nt * 16 + r15] = f2bf(a2[nt][j] * inv);
    }
  }
}

extern "C" void kernel_launch(void* const* d_in, const int* in_sizes, int n_in,
                              void* d_out, int out_size, void* d_ws, size_t ws_size,
                              hipStream_t stream) {
  (void)in_sizes; (void)n_in; (void)out_size; (void)ws_size;
  const float* x      = (const float*)d_in[0];
  const float* w_qkv  = (const float*)d_in[1];
  const float* w_proj = (const float*)d_in[2];
  const float* b_proj = (const float*)d_in[3];

  char* ws = (char*)d_ws;
  short* qkvb   = (short*)(ws);                 // 50,331,648 B [16384][1536]
  short* xb     = (short*)(ws + 50331648);      // 16,777,216 B
  short* corrU  = (short*)(ws + 67108864);      // 16,777,216 B [128][64][1024]
  short* vT     = (short*)(ws + 83886080);      // 16,777,216 B [128][64][1024]
  short* wqkvb  = (short*)(ws + 100663296);     //  1,572,864 B
  short* wprojb = (short*)(ws + 102236160);     //    524,288 B
  short* corrI    = xb;    // alias: xb dead after qkv GEMM
  short* out_attn = qkvb;  // alias: qkvb dead after corr (incl. vT epilogue)

  k_cvt3<<<dim3(4608), 256, 0, stream>>>(x, w_qkv, w_proj, xb, wqkvb, wprojb);

  k_gemm_bt<0><<<dim3(1536), 256, 0, stream>>>(xb, wqkvb, qkvb, nullptr, 16384, 1536, 512);

  k_corr<<<dim3(2048), 512, 0, stream>>>(qkvb, corrI, corrU, vT);

  k_attn<<<dim3(256), 256, 0, stream>>>(corrU, corrI, vT, out_attn);

  k_gemm_bt<1><<<dim3(512), 256, 0, stream>>>(out_attn, wprojb, d_out, b_proj, 16384, 512, 512);
}